// Round 1
// baseline (2265.536 us; speedup 1.0000x reference)
//
#include <hip/hip_runtime.h>
#include <hip/hip_bf16.h>

// Problem constants
#define B_     4
#define L_VLM_ 768
#define L_EXP_ 64
#define L_TOT_ 832
#define D_VLM_ 2048
#define D_EXP_ 1024
#define H_     8
#define DH_    256
#define HD_    2048          // H*DH
#define SCALE_ 0.0625f       // 1/sqrt(256)

// GEMM tiling
#define BM 64
#define BN 64
#define BKT 16
#define LDT 68               // padded LDS leading dim (keeps float4 alignment, 2-way banks max)

// ---------------------------------------------------------------------------
// NN core: C[64x64] tile of A(MxK) @ B(KxN).  arow[r] = base ptr of A row
// (m0 + (tid>>4) + r*16).  Bmat row-major with leading dim ldb, cols from n0.
// ---------------------------------------------------------------------------
__device__ __forceinline__ void gemm_loop_nn(
    const float* const* arow,
    const float* __restrict__ Bmat, int ldb, int n0, int K,
    float* __restrict__ As, float* __restrict__ Bs,
    float acc[4][4], int tid)
{
    const int ak = tid & 15;   // k within tile for A load
    const int am = tid >> 4;   // m base for A load (0..15)
    const int bn = tid & 63;   // n for B load
    const int bk = tid >> 6;   // k base for B load (0..3)
    const int tn = tid & 15;
    const int tm = tid >> 4;

    for (int k0 = 0; k0 < K; k0 += BKT) {
#pragma unroll
        for (int r = 0; r < 4; ++r)
            As[ak * LDT + am + r * 16] = arow[r][k0 + ak];
#pragma unroll
        for (int r = 0; r < 4; ++r)
            Bs[(bk + r * 4) * LDT + bn] =
                Bmat[(size_t)(k0 + bk + r * 4) * ldb + n0 + bn];
        __syncthreads();
#pragma unroll
        for (int kk = 0; kk < BKT; ++kk) {
            float4 a4 = *(const float4*)&As[kk * LDT + tm * 4];
            float4 b4 = *(const float4*)&Bs[kk * LDT + tn * 4];
            float a_[4] = {a4.x, a4.y, a4.z, a4.w};
            float b_[4] = {b4.x, b4.y, b4.z, b4.w};
#pragma unroll
            for (int i = 0; i < 4; ++i)
#pragma unroll
                for (int j = 0; j < 4; ++j)
                    acc[i][j] = fmaf(a_[i], b_[j], acc[i][j]);
        }
        __syncthreads();
    }
}

// ---------------------------------------------------------------------------
// NT core: C[64x64] tile of A(MxK) @ B(NxK)^T.  brow[r] = base ptr of B row
// (n0 + (tid>>4) + r*16).
// ---------------------------------------------------------------------------
__device__ __forceinline__ void gemm_loop_nt(
    const float* const* arow,
    const float* const* brow, int K,
    float* __restrict__ As, float* __restrict__ Bs,
    float acc[4][4], int tid)
{
    const int ak = tid & 15;
    const int am = tid >> 4;
    const int tn = tid & 15;
    const int tm = tid >> 4;

    for (int k0 = 0; k0 < K; k0 += BKT) {
#pragma unroll
        for (int r = 0; r < 4; ++r)
            As[ak * LDT + am + r * 16] = arow[r][k0 + ak];
#pragma unroll
        for (int r = 0; r < 4; ++r)
            Bs[ak * LDT + am + r * 16] = brow[r][k0 + ak];
        __syncthreads();
#pragma unroll
        for (int kk = 0; kk < BKT; ++kk) {
            float4 a4 = *(const float4*)&As[kk * LDT + tm * 4];
            float4 b4 = *(const float4*)&Bs[kk * LDT + tn * 4];
            float a_[4] = {a4.x, a4.y, a4.z, a4.w};
            float b_[4] = {b4.x, b4.y, b4.z, b4.w};
#pragma unroll
            for (int i = 0; i < 4; ++i)
#pragma unroll
                for (int j = 0; j < 4; ++j)
                    acc[i][j] = fmaf(a_[i], b_[j], acc[i][j]);
        }
        __syncthreads();
    }
}

// ---------------------------------------------------------------------------
// QKV projection: hidden (B*rows_pb, K) @ W (K, 2048) -> Out (B,H,L_TOT,DH)
// ---------------------------------------------------------------------------
__global__ __launch_bounds__(256) void k_proj(
    const float* __restrict__ A, const float* __restrict__ W,
    float* __restrict__ Out, int K, int rows_per_batch, int l_offset)
{
    __shared__ float As[BKT * LDT];
    __shared__ float Bs[BKT * LDT];
    const int tid = threadIdx.x;
    const int m0 = blockIdx.y * BM, n0 = blockIdx.x * BN;
    const int am = tid >> 4;

    const float* arow[4];
#pragma unroll
    for (int r = 0; r < 4; ++r)
        arow[r] = A + (size_t)(m0 + am + r * 16) * K;

    float acc[4][4] = {};
    gemm_loop_nn(arow, W, HD_, n0, K, As, Bs, acc, tid);

    const int tm = tid >> 4, tn = tid & 15;
#pragma unroll
    for (int i = 0; i < 4; ++i) {
        int m = m0 + tm * 4 + i;
        int b = m / rows_per_batch;
        int l = m - b * rows_per_batch + l_offset;
#pragma unroll
        for (int j = 0; j < 4; ++j) {
            int n = n0 + tn * 4 + j;
            int h = n >> 8, dh = n & 255;
            Out[(((size_t)b * H_ + h) * L_TOT_ + l) * DH_ + dh] = acc[i][j];
        }
    }
}

// ---------------------------------------------------------------------------
// RoPE in place on Q and K, layout (B,H,L_TOT,DH). One block per (b,h,l).
// ---------------------------------------------------------------------------
__global__ __launch_bounds__(128) void k_rope(
    float* __restrict__ Q, float* __restrict__ Kx,
    const int* __restrict__ pos)
{
    const int idx = blockIdx.x;                 // (b*H + h)*L_TOT + l
    const int l = idx % L_TOT_;
    const int b = idx / (H_ * L_TOT_);
    const int i = threadIdx.x;                  // 0..127
    const float p = (float)pos[b * L_TOT_ + l];
    // inv_freq = 10000^(-i/128) = 2^(-i * log2(10000)/128)
    const float inv = exp2f(-(float)i * 0.103810252965229910f);
    const float ang = p * inv;
    const float c = cosf(ang), s = sinf(ang);
    const size_t base = (size_t)idx * DH_;

    float x1 = Q[base + i], x2 = Q[base + i + 128];
    Q[base + i]       = x1 * c - x2 * s;
    Q[base + i + 128] = x2 * c + x1 * s;
    x1 = Kx[base + i]; x2 = Kx[base + i + 128];
    Kx[base + i]       = x1 * c - x2 * s;
    Kx[base + i + 128] = x2 * c + x1 * s;
}

// ---------------------------------------------------------------------------
// Scores: S[bh] = Q[bh] @ K[bh]^T * SCALE + mask[b]   (832 x 832 per bh)
// ---------------------------------------------------------------------------
__global__ __launch_bounds__(256) void k_scores(
    const float* __restrict__ Q, const float* __restrict__ Km,
    const float* __restrict__ mask, float* __restrict__ S)
{
    __shared__ float As[BKT * LDT];
    __shared__ float Bs[BKT * LDT];
    const int tid = threadIdx.x;
    const int bh = blockIdx.z;
    const int b = bh >> 3;
    const int m0 = blockIdx.y * BM, n0 = blockIdx.x * BN;
    const float* Qb = Q + (size_t)bh * L_TOT_ * DH_;
    const float* Kb = Km + (size_t)bh * L_TOT_ * DH_;
    const int am = tid >> 4;

    const float* arow[4];
    const float* brow[4];
#pragma unroll
    for (int r = 0; r < 4; ++r) {
        arow[r] = Qb + (size_t)(m0 + am + r * 16) * DH_;
        brow[r] = Kb + (size_t)(n0 + am + r * 16) * DH_;
    }

    float acc[4][4] = {};
    gemm_loop_nt(arow, brow, DH_, As, Bs, acc, tid);

    const int tm = tid >> 4, tn = tid & 15;
    float* Sb = S + (size_t)bh * L_TOT_ * L_TOT_;
    const float* Mb = mask + (size_t)b * L_TOT_ * L_TOT_;
#pragma unroll
    for (int i = 0; i < 4; ++i) {
        int q = m0 + tm * 4 + i;
#pragma unroll
        for (int j = 0; j < 4; ++j) {
            int kc = n0 + tn * 4 + j;
            Sb[(size_t)q * L_TOT_ + kc] =
                acc[i][j] * SCALE_ + Mb[(size_t)q * L_TOT_ + kc];
        }
    }
}

// ---------------------------------------------------------------------------
// Row softmax over 832 elements, in place. One block (256 thr) per row.
// ---------------------------------------------------------------------------
__global__ __launch_bounds__(256) void k_softmax(float* __restrict__ S)
{
    __shared__ float red[8];
    float* Sr = S + (size_t)blockIdx.x * L_TOT_;
    const int t = threadIdx.x;
    const int wave = t >> 6, lane = t & 63;

    float v[4];
    int cnt = 0;
    float lm = -1e30f;
    for (int i = t; i < L_TOT_; i += 256) {
        v[cnt] = Sr[i];
        lm = fmaxf(lm, v[cnt]);
        ++cnt;
    }
#pragma unroll
    for (int off = 32; off; off >>= 1) lm = fmaxf(lm, __shfl_down(lm, off));
    if (lane == 0) red[wave] = lm;
    __syncthreads();
    if (t == 0) {
        float m = fmaxf(fmaxf(red[0], red[1]), fmaxf(red[2], red[3]));
        red[4] = m;
    }
    __syncthreads();
    const float m = red[4];

    float lsum = 0.f;
    for (int c = 0; c < cnt; ++c) { v[c] = __expf(v[c] - m); lsum += v[c]; }
#pragma unroll
    for (int off = 32; off; off >>= 1) lsum += __shfl_down(lsum, off);
    if (lane == 0) red[wave] = lsum;
    __syncthreads();
    if (t == 0) red[5] = 1.0f / (red[0] + red[1] + red[2] + red[3]);
    __syncthreads();
    const float inv = red[5];

    cnt = 0;
    for (int i = t; i < L_TOT_; i += 256) { Sr[i] = v[cnt] * inv; ++cnt; }
}

// ---------------------------------------------------------------------------
// PV: Out(b, l, h*DH + d) = P[bh] (832x832) @ V[bh] (832x256)
// ---------------------------------------------------------------------------
__global__ __launch_bounds__(256) void k_pv(
    const float* __restrict__ P, const float* __restrict__ V,
    float* __restrict__ Out)
{
    __shared__ float As[BKT * LDT];
    __shared__ float Bs[BKT * LDT];
    const int tid = threadIdx.x;
    const int bh = blockIdx.z;
    const int b = bh >> 3, h = bh & 7;
    const int m0 = blockIdx.y * BM, n0 = blockIdx.x * BN;   // n in [0,256)
    const float* Pb = P + (size_t)bh * L_TOT_ * L_TOT_;
    const float* Vb = V + (size_t)bh * L_TOT_ * DH_;
    const int am = tid >> 4;

    const float* arow[4];
#pragma unroll
    for (int r = 0; r < 4; ++r)
        arow[r] = Pb + (size_t)(m0 + am + r * 16) * L_TOT_;

    float acc[4][4] = {};
    gemm_loop_nn(arow, Vb, DH_, n0, L_TOT_, As, Bs, acc, tid);

    const int tm = tid >> 4, tn = tid & 15;
#pragma unroll
    for (int i = 0; i < 4; ++i) {
        int q = m0 + tm * 4 + i;
#pragma unroll
        for (int j = 0; j < 4; ++j) {
            int d = n0 + tn * 4 + j;
            Out[((size_t)b * L_TOT_ + q) * HD_ + h * DH_ + d] = acc[i][j];
        }
    }
}

// ---------------------------------------------------------------------------
// Output projection: rows of attn_out (B,L_TOT,HD) @ W (HD,N) -> C (B*rows_pb, N)
// ---------------------------------------------------------------------------
__global__ __launch_bounds__(256) void k_oproj(
    const float* __restrict__ Ain, const float* __restrict__ W,
    float* __restrict__ C, int N, int rows_per_batch, int l_offset)
{
    __shared__ float As[BKT * LDT];
    __shared__ float Bs[BKT * LDT];
    const int tid = threadIdx.x;
    const int m0 = blockIdx.y * BM, n0 = blockIdx.x * BN;
    const int am = tid >> 4;

    const float* arow[4];
#pragma unroll
    for (int r = 0; r < 4; ++r) {
        int m = m0 + am + r * 16;
        int b = m / rows_per_batch;
        int rr = m - b * rows_per_batch;
        arow[r] = Ain + ((size_t)b * L_TOT_ + rr + l_offset) * HD_;
    }

    float acc[4][4] = {};
    gemm_loop_nn(arow, W, N, n0, HD_, As, Bs, acc, tid);

    const int tm = tid >> 4, tn = tid & 15;
#pragma unroll
    for (int i = 0; i < 4; ++i) {
        size_t m = m0 + tm * 4 + i;
#pragma unroll
        for (int j = 0; j < 4; ++j) {
            int n = n0 + tn * 4 + j;
            C[m * N + n] = acc[i][j];
        }
    }
}

// ---------------------------------------------------------------------------
extern "C" void kernel_launch(void* const* d_in, const int* in_sizes, int n_in,
                              void* d_out, int out_size, void* d_ws, size_t ws_size,
                              hipStream_t stream)
{
    const float* vlm_h = (const float*)d_in[0];
    const float* exp_h = (const float*)d_in[1];
    const float* mask  = (const float*)d_in[2];
    const int*   pos   = (const int*)d_in[3];
    const float* wq_v  = (const float*)d_in[4];
    const float* wk_v  = (const float*)d_in[5];
    const float* wv_v  = (const float*)d_in[6];
    const float* wo_v  = (const float*)d_in[7];
    const float* wq_e  = (const float*)d_in[8];
    const float* wk_e  = (const float*)d_in[9];
    const float* wv_e  = (const float*)d_in[10];
    const float* wo_e  = (const float*)d_in[11];
    float* out = (float*)d_out;

    float* ws = (float*)d_ws;
    const size_t QN = (size_t)B_ * H_ * L_TOT_ * DH_;        // 6,815,744
    const size_t SN = (size_t)B_ * H_ * L_TOT_ * L_TOT_;     // 22,151,168
    float* Q  = ws;
    float* K  = ws + QN;
    float* V  = ws + 2 * QN;
    float* S  = ws + 3 * QN;
    float* AO = S + SN;

    const dim3 blk(256);

    // QKV projections
    const dim3 gv(HD_ / BN, (B_ * L_VLM_) / BM);   // (32, 48)
    k_proj<<<gv, blk, 0, stream>>>(vlm_h, wq_v, Q, D_VLM_, L_VLM_, 0);
    k_proj<<<gv, blk, 0, stream>>>(vlm_h, wk_v, K, D_VLM_, L_VLM_, 0);
    k_proj<<<gv, blk, 0, stream>>>(vlm_h, wv_v, V, D_VLM_, L_VLM_, 0);
    const dim3 ge(HD_ / BN, (B_ * L_EXP_) / BM);   // (32, 4)
    k_proj<<<ge, blk, 0, stream>>>(exp_h, wq_e, Q, D_EXP_, L_EXP_, L_VLM_);
    k_proj<<<ge, blk, 0, stream>>>(exp_h, wk_e, K, D_EXP_, L_EXP_, L_VLM_);
    k_proj<<<ge, blk, 0, stream>>>(exp_h, wv_e, V, D_EXP_, L_EXP_, L_VLM_);

    // RoPE on Q, K
    k_rope<<<dim3(B_ * H_ * L_TOT_), dim3(128), 0, stream>>>(Q, K, pos);

    // Scores + softmax
    k_scores<<<dim3(L_TOT_ / BN, L_TOT_ / BM, B_ * H_), blk, 0, stream>>>(Q, K, mask, S);
    k_softmax<<<dim3(B_ * H_ * L_TOT_), blk, 0, stream>>>(S);

    // P @ V
    k_pv<<<dim3(DH_ / BN, L_TOT_ / BM, B_ * H_), blk, 0, stream>>>(S, V, AO);

    // Output projections
    k_oproj<<<dim3(HD_ / BN, (B_ * L_VLM_) / BM), blk, 0, stream>>>(
        AO, wo_v, out, HD_, L_VLM_, 0);
    k_oproj<<<dim3(D_EXP_ / BN, (B_ * L_EXP_) / BM), blk, 0, stream>>>(
        AO, wo_e, out + (size_t)B_ * L_VLM_ * HD_, D_EXP_, L_EXP_, L_VLM_);
}

// Round 3
// 691.548 us; speedup vs baseline: 3.2760x; 3.2760x over previous
//
#include <hip/hip_runtime.h>

typedef unsigned short u16;
using bf16x8 = __attribute__((ext_vector_type(8))) __bf16;
using f32x4  = __attribute__((ext_vector_type(4))) float;

// ---------------- helpers ----------------
__device__ __forceinline__ u16 f2bf(float f) {
  unsigned u = __builtin_bit_cast(unsigned, f);
  u += 0x7FFFu + ((u >> 16) & 1u);       // round-to-nearest-even
  return (u16)(u >> 16);
}
__device__ __forceinline__ float bf2f(u16 s) {
  unsigned u = ((unsigned)s) << 16;
  return __builtin_bit_cast(float, u);
}
__device__ __forceinline__ void lds16(const void* g, void* l) {
  __builtin_amdgcn_global_load_lds(
      (const __attribute__((address_space(1))) void*)g,
      (__attribute__((address_space(3))) void*)l, 16, 0, 0);
}

// ---------------------------------------------------------------------------
// 128x128 bf16 NT GEMM core. Tile: BM=128, BN=128, BK=32.
// A (M x K) row-major bf16, Bt (N x K) row-major bf16; C = A * Bt^T, f32 acc.
// 256 threads = 4 waves, wave (wm,wn) owns a 64x64 quadrant as 4x4 MFMA tiles.
// LDS XOR chunk swizzle: LDS[row][slot] (16B chunks) holds global chunk
// slot^(row&3); source pointers passed in already carry the swizzled offset.
// Staging dest = wave-uniform base + lane*16B (global_load_lds contract).
// ---------------------------------------------------------------------------
__device__ __forceinline__ void gemm128(
    const u16* a0, const u16* a1, const u16* b0, const u16* b1,
    int ksteps, int rsA, int rsB, int t, u16* As, u16* Bs, f32x4 acc[4][4])
{
  const int lane = t & 63;
  u16* dA0 = As + t * 8;          // 16B per thread
  u16* dA1 = As + t * 8 + 2048;   // +4096 bytes
  u16* dB0 = Bs + t * 8;
  u16* dB1 = Bs + t * 8 + 2048;

  const int wm = t >> 7;
  const int wn = (t >> 6) & 1;
  const int swz = (((lane >> 4) ^ (lane & 3)) * 8);
  const int fa = (wm * 64 + (lane & 15)) * 32 + swz;
  const int fb = (wn * 64 + (lane & 15)) * 32 + swz;
  (void)rsA; (void)rsB;

  for (int ks = 0; ks < ksteps; ++ks) {
    lds16(a0, dA0);
    lds16(a1, dA1);
    lds16(b0, dB0);
    lds16(b1, dB1);
    a0 += 32; a1 += 32; b0 += 32; b1 += 32;
    __syncthreads();               // compiler drains vmcnt(0) before barrier
    bf16x8 af[4], bfr[4];
#pragma unroll
    for (int i = 0; i < 4; ++i) af[i]  = *(const bf16x8*)(As + fa + i * 512);
#pragma unroll
    for (int i = 0; i < 4; ++i) bfr[i] = *(const bf16x8*)(Bs + fb + i * 512);
#pragma unroll
    for (int mt = 0; mt < 4; ++mt)
#pragma unroll
      for (int nt = 0; nt < 4; ++nt)
        acc[mt][nt] = __builtin_amdgcn_mfma_f32_16x16x32_bf16(
            af[mt], bfr[nt], acc[mt][nt], 0, 0, 0);
    __syncthreads();
  }
}

// C/D layout: col = lane&15, row = (lane>>4)*4 + reg   [m89-verified]

// ---------------------------------------------------------------------------
__global__ __launch_bounds__(256) void g_cvt(
    const float* __restrict__ X, u16* __restrict__ Y, int n4)
{
  int i = blockIdx.x * 256 + threadIdx.x;
  if (i < n4) {
    float4 f = ((const float4*)X)[i];
    ushort4 u;
    u.x = f2bf(f.x); u.y = f2bf(f.y); u.z = f2bf(f.z); u.w = f2bf(f.w);
    ((ushort4*)Y)[i] = u;
  }
}

// ---------------------------------------------------------------------------
// W (Krows x Ncols) f32  ->  Wt (Ncols x Krows) bf16
// ---------------------------------------------------------------------------
__global__ __launch_bounds__(256) void g_transpose(
    const float* __restrict__ W, u16* __restrict__ Wt, int Krows, int Ncols)
{
  __shared__ float T[32][33];
  const int tx = threadIdx.x & 31, ty = threadIdx.x >> 5;
  const int k0 = blockIdx.y * 32, n0 = blockIdx.x * 32;
#pragma unroll
  for (int r = 0; r < 4; ++r)
    T[ty + r * 8][tx] = W[(size_t)(k0 + ty + r * 8) * Ncols + n0 + tx];
  __syncthreads();
#pragma unroll
  for (int r = 0; r < 4; ++r)
    Wt[(size_t)(n0 + ty + r * 8) * Krows + k0 + tx] = f2bf(T[tx][ty + r * 8]);
}

// ---------------------------------------------------------------------------
// Q/K projection: X (rows x Kdim) @ Wt^T -> Out (bh, 896pad, 256) bf16
// ---------------------------------------------------------------------------
__global__ __launch_bounds__(256) void g_proj_qk(
    const u16* __restrict__ X, const u16* __restrict__ Wt,
    u16* __restrict__ Out, int Kdim, int rows_pb, int l_off)
{
  __shared__ u16 As[4096], Bs[4096];
  const int t = threadIdx.x;
  const int m0 = blockIdx.y * 128, n0 = blockIdx.x * 128;
  const int r0 = t >> 2;
  const int cs = ((t & 3) ^ (r0 & 3)) * 8;
  const u16* a0 = X + (size_t)(m0 + r0) * Kdim + cs;
  const u16* a1 = X + (size_t)(m0 + r0 + 64) * Kdim + cs;
  const u16* b0 = Wt + (size_t)(n0 + r0) * Kdim + cs;
  const u16* b1 = Wt + (size_t)(n0 + r0 + 64) * Kdim + cs;

  f32x4 acc[4][4] = {};
  gemm128(a0, a1, b0, b1, Kdim >> 5, Kdim, Kdim, t, As, Bs, acc);

  const int lane = t & 63;
  const int rbase = m0 + (t >> 7) * 64 + ((lane >> 4) << 2);
  const int cbase = n0 + ((t >> 6) & 1) * 64 + (lane & 15);
#pragma unroll
  for (int mt = 0; mt < 4; ++mt) {
#pragma unroll
    for (int r = 0; r < 4; ++r) {
      int m = rbase + mt * 16 + r;
      int b = m / rows_pb;
      int l = m - b * rows_pb + l_off;
#pragma unroll
      for (int nt = 0; nt < 4; ++nt) {
        int n = cbase + nt * 16;
        Out[(((size_t)(b * 8 + (n >> 8))) * 896 + l) * 256 + (n & 255)] =
            f2bf(acc[mt][nt][r]);
      }
    }
  }
}

// ---------------------------------------------------------------------------
// V projection: writes Vt (bh, 256, 896pad) bf16 (transposed for PV NT GEMM)
// NOTE: Vt aliases Wqv+Wkv — must launch after Q/K projections.
// ---------------------------------------------------------------------------
__global__ __launch_bounds__(256) void g_proj_v(
    const u16* __restrict__ X, const u16* __restrict__ Wt,
    u16* __restrict__ Vt, int Kdim, int rows_pb, int l_off)
{
  __shared__ u16 As[4096], Bs[4096];
  const int t = threadIdx.x;
  const int m0 = blockIdx.y * 128, n0 = blockIdx.x * 128;
  const int r0 = t >> 2;
  const int cs = ((t & 3) ^ (r0 & 3)) * 8;
  const u16* a0 = X + (size_t)(m0 + r0) * Kdim + cs;
  const u16* a1 = X + (size_t)(m0 + r0 + 64) * Kdim + cs;
  const u16* b0 = Wt + (size_t)(n0 + r0) * Kdim + cs;
  const u16* b1 = Wt + (size_t)(n0 + r0 + 64) * Kdim + cs;

  f32x4 acc[4][4] = {};
  gemm128(a0, a1, b0, b1, Kdim >> 5, Kdim, Kdim, t, As, Bs, acc);

  const int lane = t & 63;
  const int rbase = m0 + (t >> 7) * 64 + ((lane >> 4) << 2);
  const int cbase = n0 + ((t >> 6) & 1) * 64 + (lane & 15);
#pragma unroll
  for (int mt = 0; mt < 4; ++mt) {
    int mb = rbase + mt * 16;
    int b = mb / rows_pb;
    int l = mb - b * rows_pb + l_off;          // 4-aligned, no batch crossing
#pragma unroll
    for (int nt = 0; nt < 4; ++nt) {
      int n = cbase + nt * 16;
      ushort4 p;
      p.x = f2bf(acc[mt][nt][0]); p.y = f2bf(acc[mt][nt][1]);
      p.z = f2bf(acc[mt][nt][2]); p.w = f2bf(acc[mt][nt][3]);
      *(ushort4*)&Vt[(((size_t)(b * 8 + (n >> 8))) * 256 + (n & 255)) * 896 + l] = p;
    }
  }
}

// ---------------------------------------------------------------------------
// RoPE in place on bf16 Q,K (bh, 896pad, 256); grid = bh*832 real rows
// ---------------------------------------------------------------------------
__global__ __launch_bounds__(128) void g_rope(
    u16* __restrict__ Q, u16* __restrict__ Kx, const int* __restrict__ pos)
{
  const int blk = blockIdx.x;
  const int l = blk % 832, bh = blk / 832, b = bh >> 3;
  const int i = threadIdx.x;
  const float p = (float)pos[b * 832 + l];
  const float inv = exp2f(-(float)i * 0.103810252965229910f);  // log2(1e4)/128
  const float ang = p * inv;
  const float c = cosf(ang), s = sinf(ang);
  const size_t base = ((size_t)bh * 896 + l) * 256;

  float x1 = bf2f(Q[base + i]), x2 = bf2f(Q[base + i + 128]);
  Q[base + i]       = f2bf(x1 * c - x2 * s);
  Q[base + i + 128] = f2bf(x2 * c + x1 * s);
  x1 = bf2f(Kx[base + i]); x2 = bf2f(Kx[base + i + 128]);
  Kx[base + i]       = f2bf(x1 * c - x2 * s);
  Kx[base + i + 128] = f2bf(x2 * c + x1 * s);
}

// ---------------------------------------------------------------------------
// Scores: S[bh] = Q @ K^T * SCALE + mask, f32. S is 832 rows x 896 cols per bh
// (pad q-rows NOT stored; pad k-cols stored as -1e30).
// ---------------------------------------------------------------------------
__global__ __launch_bounds__(256) void g_scores(
    const u16* __restrict__ Qb, const u16* __restrict__ Kb,
    const float* __restrict__ mask, float* __restrict__ S)
{
  __shared__ u16 As[4096], Bs[4096];
  const int t = threadIdx.x;
  const int bh = blockIdx.z;
  const int m0 = blockIdx.y * 128, n0 = blockIdx.x * 128;
  const int r0 = t >> 2;
  const int cs = ((t & 3) ^ (r0 & 3)) * 8;
  const u16* Qa = Qb + (size_t)bh * 896 * 256;
  const u16* Ka = Kb + (size_t)bh * 896 * 256;
  const u16* a0 = Qa + (size_t)(m0 + r0) * 256 + cs;
  const u16* a1 = Qa + (size_t)(m0 + r0 + 64) * 256 + cs;
  const u16* b0 = Ka + (size_t)(n0 + r0) * 256 + cs;
  const u16* b1 = Ka + (size_t)(n0 + r0 + 64) * 256 + cs;

  f32x4 acc[4][4] = {};
  gemm128(a0, a1, b0, b1, 8, 256, 256, t, As, Bs, acc);

  const int lane = t & 63;
  const int rbase = m0 + (t >> 7) * 64 + ((lane >> 4) << 2);
  const int cbase = n0 + ((t >> 6) & 1) * 64 + (lane & 15);
  float* Sb = S + (size_t)bh * 832 * 896;
  const float* Mb = mask + (size_t)(bh >> 3) * 832 * 832;
#pragma unroll
  for (int mt = 0; mt < 4; ++mt) {
#pragma unroll
    for (int r = 0; r < 4; ++r) {
      int q = rbase + mt * 16 + r;
      if (q < 832) {
#pragma unroll
        for (int nt = 0; nt < 4; ++nt) {
          int kc = cbase + nt * 16;
          float v = -1e30f;
          if (kc < 832)
            v = acc[mt][nt][r] * 0.0625f + Mb[(size_t)q * 832 + kc];
          Sb[(size_t)q * 896 + kc] = v;
        }
      }
    }
  }
}

// ---------------------------------------------------------------------------
// Row softmax over 896 f32 -> 896 bf16, IN PLACE over the same row
// (P row i overlays S row i: 896 bf16 within the 3584-byte row).
// Block reads its whole f32 row into registers before any write.
// ---------------------------------------------------------------------------
__global__ __launch_bounds__(256) void g_softmax(
    float* __restrict__ S)
{
  __shared__ float red[8];
  float* Sr = S + (size_t)blockIdx.x * 896;
  u16* Pr = (u16*)Sr;                  // stride 1792 u16 == 896 f32 row
  const int t = threadIdx.x;
  const int wave = t >> 6, lane = t & 63;

  float v[4];
  int cnt = 0;
  float lm = -3e38f;
  for (int i = t; i < 896; i += 256) { v[cnt] = Sr[i]; lm = fmaxf(lm, v[cnt]); ++cnt; }
#pragma unroll
  for (int off = 32; off; off >>= 1) lm = fmaxf(lm, __shfl_down(lm, off));
  if (lane == 0) red[wave] = lm;
  __syncthreads();
  if (t == 0) red[4] = fmaxf(fmaxf(red[0], red[1]), fmaxf(red[2], red[3]));
  __syncthreads();
  const float m = red[4];

  float lsum = 0.f;
  for (int c = 0; c < cnt; ++c) { v[c] = __expf(v[c] - m); lsum += v[c]; }
#pragma unroll
  for (int off = 32; off; off >>= 1) lsum += __shfl_down(lsum, off);
  if (lane == 0) red[wave] = lsum;
  __syncthreads();
  if (t == 0) red[5] = 1.0f / (red[0] + red[1] + red[2] + red[3]);
  __syncthreads();
  const float inv = red[5];

  cnt = 0;
  for (int i = t; i < 896; i += 256) { Pr[i] = f2bf(v[cnt] * inv); ++cnt; }
}

// ---------------------------------------------------------------------------
// PV: AO(b,l,h*256+dh) = P[bh](832x896, stride 1792 u16) @ Vt[bh](256x896)^T
// Rows >= 832 of P don't exist (reads land in later ws regions; results
// discarded by l<832 guard).
// ---------------------------------------------------------------------------
__global__ __launch_bounds__(256) void g_pv(
    const u16* __restrict__ P, const u16* __restrict__ Vt,
    u16* __restrict__ AO)
{
  __shared__ u16 As[4096], Bs[4096];
  const int t = threadIdx.x;
  const int bh = blockIdx.z;
  const int m0 = blockIdx.y * 128, n0 = blockIdx.x * 128;
  const int r0 = t >> 2;
  const int cs = ((t & 3) ^ (r0 & 3)) * 8;
  const u16* Pa = P + (size_t)bh * 832 * 1792;
  const u16* Va = Vt + (size_t)bh * 256 * 896;
  const u16* a0 = Pa + (size_t)(m0 + r0) * 1792 + cs;
  const u16* a1 = Pa + (size_t)(m0 + r0 + 64) * 1792 + cs;
  const u16* b0 = Va + (size_t)(n0 + r0) * 896 + cs;
  const u16* b1 = Va + (size_t)(n0 + r0 + 64) * 896 + cs;

  f32x4 acc[4][4] = {};
  gemm128(a0, a1, b0, b1, 28, 1792, 896, t, As, Bs, acc);

  const int lane = t & 63;
  const int rbase = m0 + (t >> 7) * 64 + ((lane >> 4) << 2);
  const int cbase = n0 + ((t >> 6) & 1) * 64 + (lane & 15);
  const int b = bh >> 3, h = bh & 7;
#pragma unroll
  for (int mt = 0; mt < 4; ++mt) {
#pragma unroll
    for (int r = 0; r < 4; ++r) {
      int l = rbase + mt * 16 + r;
      if (l < 832) {
#pragma unroll
        for (int nt = 0; nt < 4; ++nt) {
          int dh = cbase + nt * 16;
          AO[((size_t)b * 832 + l) * 2048 + h * 256 + dh] = f2bf(acc[mt][nt][r]);
        }
      }
    }
  }
}

// ---------------------------------------------------------------------------
// Output projection: AO rows @ Wt^T -> f32 out (Kdim = 2048)
// ---------------------------------------------------------------------------
__global__ __launch_bounds__(256) void g_oproj(
    const u16* __restrict__ AO, const u16* __restrict__ Wt,
    float* __restrict__ C, int N, int rows_pb, int l_off)
{
  __shared__ u16 As[4096], Bs[4096];
  const int t = threadIdx.x;
  const int m0 = blockIdx.y * 128, n0 = blockIdx.x * 128;
  const int r0 = t >> 2;
  const int cs = ((t & 3) ^ (r0 & 3)) * 8;
  int mr0 = m0 + r0, mr1 = m0 + r0 + 64;
  int ba = mr0 / rows_pb, bb = mr1 / rows_pb;
  const u16* a0 = AO + ((size_t)ba * 832 + (mr0 - ba * rows_pb) + l_off) * 2048 + cs;
  const u16* a1 = AO + ((size_t)bb * 832 + (mr1 - bb * rows_pb) + l_off) * 2048 + cs;
  const u16* b0 = Wt + (size_t)(n0 + r0) * 2048 + cs;
  const u16* b1 = Wt + (size_t)(n0 + r0 + 64) * 2048 + cs;

  f32x4 acc[4][4] = {};
  gemm128(a0, a1, b0, b1, 64, 2048, 2048, t, As, Bs, acc);

  const int lane = t & 63;
  const int rbase = m0 + (t >> 7) * 64 + ((lane >> 4) << 2);
  const int cbase = n0 + ((t >> 6) & 1) * 64 + (lane & 15);
#pragma unroll
  for (int mt = 0; mt < 4; ++mt)
#pragma unroll
    for (int r = 0; r < 4; ++r) {
      size_t m = rbase + mt * 16 + r;
#pragma unroll
      for (int nt = 0; nt < 4; ++nt)
        C[m * N + cbase + nt * 16] = acc[mt][nt][r];
    }
}

// ---------------------------------------------------------------------------
extern "C" void kernel_launch(void* const* d_in, const int* in_sizes, int n_in,
                              void* d_out, int out_size, void* d_ws, size_t ws_size,
                              hipStream_t stream)
{
  const float* vlm_h = (const float*)d_in[0];
  const float* exp_h = (const float*)d_in[1];
  const float* mask  = (const float*)d_in[2];
  const int*   pos   = (const int*)d_in[3];
  const float* wq_v  = (const float*)d_in[4];
  const float* wk_v  = (const float*)d_in[5];
  const float* wv_v  = (const float*)d_in[6];
  const float* wo_v  = (const float*)d_in[7];
  const float* wq_e  = (const float*)d_in[8];
  const float* wk_e  = (const float*)d_in[9];
  const float* wv_e  = (const float*)d_in[10];
  const float* wo_e  = (const float*)d_in[11];
  float* out = (float*)d_out;

  // ---- workspace layout (total 188.2 MB; round-1 proved >= 197.6 MB) ----
  float* S = (float*)d_ws;                       // 32 * 832 * 896 f32 (95.4 MB)
  u16* U = (u16*)((char*)d_ws + (size_t)32 * 832 * 896 * 4);
  u16* Xv  = U; U += (size_t)4 * 768 * 2048;     // 12.6 MB
  u16* Xe  = U; U += (size_t)4 * 64 * 1024;      //  0.5 MB
  u16* Wqv = U; U += (size_t)2048 * 2048;        //  8.4 MB  (dead after Q proj)
  u16* Wkv = U; U += (size_t)2048 * 2048;        //  8.4 MB  (dead after K proj)
  u16* Wvv = U; U += (size_t)2048 * 2048;        //  8.4 MB
  u16* Wqe = U; U += (size_t)1024 * 2048;        //  4.2 MB
  u16* Wke = U; U += (size_t)1024 * 2048;        //  4.2 MB
  u16* Wve = U; U += (size_t)1024 * 2048;        //  4.2 MB
  u16* Wov = U; U += (size_t)2048 * 2048;        //  8.4 MB
  u16* Woe = U; U += (size_t)1024 * 2048;        //  4.2 MB
  u16* Qb  = U; U += (size_t)32 * 896 * 256;     // 14.7 MB (dead after scores)
  u16* Kb  = U; U += (size_t)32 * 896 * 256;     // 14.7 MB
  u16* Vt  = Wqv;    // alias: 14.7 MB into Wqv+Wkv (16.8 MB), written after Q/K proj
  u16* AO  = Qb;     // alias: 13.6 MB into Qb (14.7 MB), written after scores
  u16* Pm  = (u16*)S; // alias: probs overlay scores rows (stride 1792 u16)

  const dim3 blk(256);

  // convert activations to bf16
  g_cvt<<<dim3(1572864 / 256), blk, 0, stream>>>(vlm_h, Xv, 1572864);
  g_cvt<<<dim3(65536 / 256),   blk, 0, stream>>>(exp_h, Xe, 65536);

  // transpose weights to (N,K) bf16
  g_transpose<<<dim3(64, 64), blk, 0, stream>>>(wq_v, Wqv, 2048, 2048);
  g_transpose<<<dim3(64, 64), blk, 0, stream>>>(wk_v, Wkv, 2048, 2048);
  g_transpose<<<dim3(64, 64), blk, 0, stream>>>(wv_v, Wvv, 2048, 2048);
  g_transpose<<<dim3(64, 64), blk, 0, stream>>>(wo_v, Wov, 2048, 2048);
  g_transpose<<<dim3(64, 32), blk, 0, stream>>>(wq_e, Wqe, 1024, 2048);
  g_transpose<<<dim3(64, 32), blk, 0, stream>>>(wk_e, Wke, 1024, 2048);
  g_transpose<<<dim3(64, 32), blk, 0, stream>>>(wv_e, Wve, 1024, 2048);
  g_transpose<<<dim3(32, 64), blk, 0, stream>>>(wo_e, Woe, 2048, 1024);

  // Q and K projections first (they consume Wqv/Wkv which Vt will overwrite)
  g_proj_qk<<<dim3(16, 24), blk, 0, stream>>>(Xv, Wqv, Qb, 2048, 768, 0);
  g_proj_qk<<<dim3(16, 2),  blk, 0, stream>>>(Xe, Wqe, Qb, 1024, 64, 768);
  g_proj_qk<<<dim3(16, 24), blk, 0, stream>>>(Xv, Wkv, Kb, 2048, 768, 0);
  g_proj_qk<<<dim3(16, 2),  blk, 0, stream>>>(Xe, Wke, Kb, 1024, 64, 768);
  // V projections (write Vt over Wqv/Wkv)
  g_proj_v <<<dim3(16, 24), blk, 0, stream>>>(Xv, Wvv, Vt, 2048, 768, 0);
  g_proj_v <<<dim3(16, 2),  blk, 0, stream>>>(Xe, Wve, Vt, 1024, 64, 768);

  // RoPE
  g_rope<<<dim3(32 * 832), dim3(128), 0, stream>>>(Qb, Kb, pos);

  // attention
  g_scores <<<dim3(7, 7, 32), blk, 0, stream>>>(Qb, Kb, mask, S);
  g_softmax<<<dim3(32 * 832), blk, 0, stream>>>(S);
  g_pv     <<<dim3(2, 7, 32), blk, 0, stream>>>(Pm, Vt, AO);

  // output projections
  g_oproj<<<dim3(16, 24), blk, 0, stream>>>(AO, Wov, out, 2048, 768, 0);
  g_oproj<<<dim3(8, 2),   blk, 0, stream>>>(AO, Woe, out + (size_t)4 * 768 * 2048,
                                            1024, 64, 768);
}

// Round 4
// 686.919 us; speedup vs baseline: 3.2981x; 1.0067x over previous
//
#include <hip/hip_runtime.h>

typedef unsigned short u16;
using bf16x8 = __attribute__((ext_vector_type(8))) __bf16;
using f32x4  = __attribute__((ext_vector_type(4))) float;

// ---------------- helpers ----------------
__device__ __forceinline__ u16 f2bf(float f) {
  unsigned u = __builtin_bit_cast(unsigned, f);
  u += 0x7FFFu + ((u >> 16) & 1u);       // round-to-nearest-even
  return (u16)(u >> 16);
}
__device__ __forceinline__ float bf2f(u16 s) {
  unsigned u = ((unsigned)s) << 16;
  return __builtin_bit_cast(float, u);
}
__device__ __forceinline__ void lds16(const void* g, void* l) {
  __builtin_amdgcn_global_load_lds(
      (const __attribute__((address_space(1))) void*)g,
      (__attribute__((address_space(3))) void*)l, 16, 0, 0);
}

// ---------------------------------------------------------------------------
// 128x128 bf16 NT GEMM core (as round 3). BM=BN=128, BK=32, 256 thr / 4 waves.
// ---------------------------------------------------------------------------
__device__ __forceinline__ void gemm128(
    const u16* a0, const u16* a1, const u16* b0, const u16* b1,
    int ksteps, int t, u16* As, u16* Bs, f32x4 acc[4][4])
{
  const int lane = t & 63;
  u16* dA0 = As + t * 8;
  u16* dA1 = As + t * 8 + 2048;
  u16* dB0 = Bs + t * 8;
  u16* dB1 = Bs + t * 8 + 2048;

  const int wm = t >> 7;
  const int wn = (t >> 6) & 1;
  const int swz = (((lane >> 4) ^ (lane & 3)) * 8);
  const int fa = (wm * 64 + (lane & 15)) * 32 + swz;
  const int fb = (wn * 64 + (lane & 15)) * 32 + swz;

  for (int ks = 0; ks < ksteps; ++ks) {
    lds16(a0, dA0);
    lds16(a1, dA1);
    lds16(b0, dB0);
    lds16(b1, dB1);
    a0 += 32; a1 += 32; b0 += 32; b1 += 32;
    __syncthreads();
    bf16x8 af[4], bfr[4];
#pragma unroll
    for (int i = 0; i < 4; ++i) af[i]  = *(const bf16x8*)(As + fa + i * 512);
#pragma unroll
    for (int i = 0; i < 4; ++i) bfr[i] = *(const bf16x8*)(Bs + fb + i * 512);
#pragma unroll
    for (int mt = 0; mt < 4; ++mt)
#pragma unroll
      for (int nt = 0; nt < 4; ++nt)
        acc[mt][nt] = __builtin_amdgcn_mfma_f32_16x16x32_bf16(
            af[mt], bfr[nt], acc[mt][nt], 0, 0, 0);
    __syncthreads();
  }
}
// C/D layout: col = lane&15, row = (lane>>4)*4 + reg   [m89-verified]

// ---------------------------------------------------------------------------
__global__ __launch_bounds__(256) void g_cvt(
    const float* __restrict__ X, u16* __restrict__ Y, int n4)
{
  int i = blockIdx.x * 256 + threadIdx.x;
  if (i < n4) {
    float4 f = ((const float4*)X)[i];
    ushort4 u;
    u.x = f2bf(f.x); u.y = f2bf(f.y); u.z = f2bf(f.z); u.w = f2bf(f.w);
    ((ushort4*)Y)[i] = u;
  }
}

// ---------------------------------------------------------------------------
__global__ __launch_bounds__(256) void g_transpose(
    const float* __restrict__ W, u16* __restrict__ Wt, int Krows, int Ncols)
{
  __shared__ float T[32][33];
  const int tx = threadIdx.x & 31, ty = threadIdx.x >> 5;
  const int k0 = blockIdx.y * 32, n0 = blockIdx.x * 32;
#pragma unroll
  for (int r = 0; r < 4; ++r)
    T[ty + r * 8][tx] = W[(size_t)(k0 + ty + r * 8) * Ncols + n0 + tx];
  __syncthreads();
#pragma unroll
  for (int r = 0; r < 4; ++r)
    Wt[(size_t)(n0 + ty + r * 8) * Krows + k0 + tx] = f2bf(T[tx][ty + r * 8]);
}

// ---------------------------------------------------------------------------
// Q/K projection -> (bh, 832, 256) bf16
// ---------------------------------------------------------------------------
__global__ __launch_bounds__(256) void g_proj_qk(
    const u16* __restrict__ X, const u16* __restrict__ Wt,
    u16* __restrict__ Out, int Kdim, int rows_pb, int l_off)
{
  __shared__ u16 As[4096], Bs[4096];
  const int t = threadIdx.x;
  const int m0 = blockIdx.y * 128, n0 = blockIdx.x * 128;
  const int r0 = t >> 2;
  const int cs = ((t & 3) ^ (r0 & 3)) * 8;
  const u16* a0 = X + (size_t)(m0 + r0) * Kdim + cs;
  const u16* a1 = X + (size_t)(m0 + r0 + 64) * Kdim + cs;
  const u16* b0 = Wt + (size_t)(n0 + r0) * Kdim + cs;
  const u16* b1 = Wt + (size_t)(n0 + r0 + 64) * Kdim + cs;

  f32x4 acc[4][4] = {};
  gemm128(a0, a1, b0, b1, Kdim >> 5, t, As, Bs, acc);

  const int lane = t & 63;
  const int rbase = m0 + (t >> 7) * 64 + ((lane >> 4) << 2);
  const int cbase = n0 + ((t >> 6) & 1) * 64 + (lane & 15);
#pragma unroll
  for (int mt = 0; mt < 4; ++mt) {
#pragma unroll
    for (int r = 0; r < 4; ++r) {
      int m = rbase + mt * 16 + r;
      int b = m / rows_pb;
      int l = m - b * rows_pb + l_off;
#pragma unroll
      for (int nt = 0; nt < 4; ++nt) {
        int n = cbase + nt * 16;
        Out[(((size_t)(b * 8 + (n >> 8))) * 832 + l) * 256 + (n & 255)] =
            f2bf(acc[mt][nt][r]);
      }
    }
  }
}

// ---------------------------------------------------------------------------
// V projection -> Vt (bh, 256, 832) bf16 (dh-major for PV staging)
// ---------------------------------------------------------------------------
__global__ __launch_bounds__(256) void g_proj_v(
    const u16* __restrict__ X, const u16* __restrict__ Wt,
    u16* __restrict__ Vt, int Kdim, int rows_pb, int l_off)
{
  __shared__ u16 As[4096], Bs[4096];
  const int t = threadIdx.x;
  const int m0 = blockIdx.y * 128, n0 = blockIdx.x * 128;
  const int r0 = t >> 2;
  const int cs = ((t & 3) ^ (r0 & 3)) * 8;
  const u16* a0 = X + (size_t)(m0 + r0) * Kdim + cs;
  const u16* a1 = X + (size_t)(m0 + r0 + 64) * Kdim + cs;
  const u16* b0 = Wt + (size_t)(n0 + r0) * Kdim + cs;
  const u16* b1 = Wt + (size_t)(n0 + r0 + 64) * Kdim + cs;

  f32x4 acc[4][4] = {};
  gemm128(a0, a1, b0, b1, Kdim >> 5, t, As, Bs, acc);

  const int lane = t & 63;
  const int rbase = m0 + (t >> 7) * 64 + ((lane >> 4) << 2);
  const int cbase = n0 + ((t >> 6) & 1) * 64 + (lane & 15);
#pragma unroll
  for (int mt = 0; mt < 4; ++mt) {
    int mb = rbase + mt * 16;
    int b = mb / rows_pb;
    int l = mb - b * rows_pb + l_off;
#pragma unroll
    for (int nt = 0; nt < 4; ++nt) {
      int n = cbase + nt * 16;
      ushort4 p;
      p.x = f2bf(acc[mt][nt][0]); p.y = f2bf(acc[mt][nt][1]);
      p.z = f2bf(acc[mt][nt][2]); p.w = f2bf(acc[mt][nt][3]);
      *(ushort4*)&Vt[(((size_t)(b * 8 + (n >> 8))) * 256 + (n & 255)) * 832 + l] = p;
    }
  }
}

// ---------------------------------------------------------------------------
// RoPE in place on bf16 Q,K (bh, 832, 256). Q additionally scaled by 1/16.
// ---------------------------------------------------------------------------
__global__ __launch_bounds__(128) void g_rope(
    u16* __restrict__ Q, u16* __restrict__ Kx, const int* __restrict__ pos)
{
  const int blk = blockIdx.x;
  const int l = blk % 832, bh = blk / 832, b = bh >> 3;
  const int i = threadIdx.x;
  const float p = (float)pos[b * 832 + l];
  const float inv = exp2f(-(float)i * 0.103810252965229910f);  // log2(1e4)/128
  const float ang = p * inv;
  const float c = cosf(ang), s = sinf(ang);
  const size_t base = ((size_t)bh * 832 + l) * 256;

  float x1 = bf2f(Q[base + i]), x2 = bf2f(Q[base + i + 128]);
  Q[base + i]       = f2bf((x1 * c - x2 * s) * 0.0625f);
  Q[base + i + 128] = f2bf((x2 * c + x1 * s) * 0.0625f);
  x1 = bf2f(Kx[base + i]); x2 = bf2f(Kx[base + i + 128]);
  Kx[base + i]       = f2bf(x1 * c - x2 * s);
  Kx[base + i + 128] = f2bf(x2 * c + x1 * s);
}

// ---------------------------------------------------------------------------
// Attention tile helpers. Block = 128 threads (2 waves), q-tile 64
// (wave = 32 q rows), key-tile 32, 26 key-tiles (832 exact).
// K LDS tile: [32 seq][256 dh] bf16, 16B-chunk XOR swizzle slot=chunk^(row&7).
// V LDS tile: [256 dh][32 seq] bf16, no swizzle needed (64 B rows).
// ---------------------------------------------------------------------------
__device__ __forceinline__ void stage_k_tile(const u16* src, u16* Ks, int t) {
#pragma unroll
  for (int p = 0; p < 8; ++p) {
    int row = p * 4 + (t >> 5);
    int chunk = (t & 31) ^ (row & 7);
    lds16(src + row * 256 + chunk * 8, Ks + p * 1024 + t * 8);
  }
}
__device__ __forceinline__ void stage_v_tile(const u16* src, u16* Vs, int t) {
#pragma unroll
  for (int p = 0; p < 8; ++p) {
    int dh = p * 32 + (t >> 2);
    lds16(src + (size_t)dh * 832 + (t & 3) * 8, Vs + p * 1024 + t * 8);
  }
}

// S-phase: sa[mt][nt] += Q(2x16 rows) @ K_tile(32 keys)^T over dh=256
__device__ __forceinline__ void s_mfma(
    const bf16x8 qf[2][8], const u16* Ks, int lane, f32x4 sa[2][2])
{
#pragma unroll
  for (int ks = 0; ks < 8; ++ks) {
#pragma unroll
    for (int nt = 0; nt < 2; ++nt) {
      int row = nt * 16 + (lane & 15);
      bf16x8 kb = *(const bf16x8*)(
          Ks + row * 256 + (((ks * 4 + (lane >> 4)) ^ (lane & 7)) * 8));
#pragma unroll
      for (int mt = 0; mt < 2; ++mt)
        sa[mt][nt] = __builtin_amdgcn_mfma_f32_16x16x32_bf16(
            qf[mt][ks], kb, sa[mt][nt], 0, 0, 0);
    }
  }
}

// ---------------------------------------------------------------------------
// Kernel A: per-row online softmax stats (m, l). Grid (13, 32), 128 thr.
// ---------------------------------------------------------------------------
__global__ __launch_bounds__(128) void g_stats(
    const u16* __restrict__ Qb, const u16* __restrict__ Kb,
    const float* __restrict__ mask, float* __restrict__ Marr,
    float* __restrict__ Larr)
{
  __shared__ __align__(16) u16 Ks[8192];
  const int t = threadIdx.x;
  const int lane = t & 63, w = t >> 6;
  const int bh = blockIdx.y, b = bh >> 3;
  const int q0 = blockIdx.x * 64;
  const u16* Ksrc = Kb + (size_t)bh * 832 * 256;
  const float* Mrow = mask + (size_t)b * 832 * 832;

  bf16x8 qf[2][8];
#pragma unroll
  for (int mt = 0; mt < 2; ++mt)
#pragma unroll
    for (int kf = 0; kf < 8; ++kf)
      qf[mt][kf] = *(const bf16x8*)(
          Qb + ((size_t)bh * 832 + q0 + w * 32 + mt * 16 + (lane & 15)) * 256 +
          kf * 32 + (lane >> 4) * 8);

  float mrun[2][4], lrun[2][4];
#pragma unroll
  for (int mt = 0; mt < 2; ++mt)
#pragma unroll
    for (int r = 0; r < 4; ++r) { mrun[mt][r] = -3e38f; lrun[mt][r] = 0.f; }

  for (int kt = 0; kt < 26; ++kt) {
    __syncthreads();
    stage_k_tile(Ksrc + kt * 32 * 256, Ks, t);
    __syncthreads();

    f32x4 sa[2][2] = {};
    s_mfma(qf, Ks, lane, sa);

#pragma unroll
    for (int mt = 0; mt < 2; ++mt)
#pragma unroll
      for (int r = 0; r < 4; ++r) {
        int q = q0 + w * 32 + mt * 16 + ((lane >> 4) << 2) + r;
        const float* mrp = Mrow + (size_t)q * 832 + kt * 32 + (lane & 15);
        float v0 = sa[mt][0][r] + mrp[0];
        float v1 = sa[mt][1][r] + mrp[16];
        float mx = fmaxf(v0, v1);
        mx = fmaxf(mx, __shfl_xor(mx, 1));
        mx = fmaxf(mx, __shfl_xor(mx, 2));
        mx = fmaxf(mx, __shfl_xor(mx, 4));
        mx = fmaxf(mx, __shfl_xor(mx, 8));
        float mn = fmaxf(mrun[mt][r], mx);
        float al = __expf(mrun[mt][r] - mn);
        float rs = __expf(v0 - mn) + __expf(v1 - mn);
        rs += __shfl_xor(rs, 1);
        rs += __shfl_xor(rs, 2);
        rs += __shfl_xor(rs, 4);
        rs += __shfl_xor(rs, 8);
        lrun[mt][r] = lrun[mt][r] * al + rs;
        mrun[mt][r] = mn;
      }
  }

  if ((lane & 15) == 0) {
#pragma unroll
    for (int mt = 0; mt < 2; ++mt)
#pragma unroll
      for (int r = 0; r < 4; ++r) {
        int q = q0 + w * 32 + mt * 16 + ((lane >> 4) << 2) + r;
        Marr[(size_t)bh * 832 + q] = mrun[mt][r];
        Larr[(size_t)bh * 832 + q] = lrun[mt][r];
      }
  }
}

// ---------------------------------------------------------------------------
// Kernel B: recompute S, apply exp((s+mask)-m)/l, O += P @ V. Grid (13, 32).
// P wave-private LDS slice [32 rows][32 cols] (64 B rows), 16B-chunk swizzle
// slot = chunk ^ ((row>>2)&3) -> conflict-even for C-writes and A-reads.
// ---------------------------------------------------------------------------
__global__ __launch_bounds__(128) void g_attn_pv(
    const u16* __restrict__ Qb, const u16* __restrict__ Kb,
    const u16* __restrict__ Vt, const float* __restrict__ mask,
    const float* __restrict__ Marr, const float* __restrict__ Larr,
    u16* __restrict__ AO)
{
  __shared__ __align__(16) u16 Ks[8192];
  __shared__ __align__(16) u16 Vs[8192];
  __shared__ __align__(16) u16 Ps[2048];
  const int t = threadIdx.x;
  const int lane = t & 63, w = t >> 6;
  const int wbase = w * 1024;
  const int bh = blockIdx.y, b = bh >> 3, h = bh & 7;
  const int q0 = blockIdx.x * 64;
  const u16* Ksrc = Kb + (size_t)bh * 832 * 256;
  const u16* Vsrc = Vt + (size_t)bh * 256 * 832;
  const float* Mrow = mask + (size_t)b * 832 * 832;

  bf16x8 qf[2][8];
#pragma unroll
  for (int mt = 0; mt < 2; ++mt)
#pragma unroll
    for (int kf = 0; kf < 8; ++kf)
      qf[mt][kf] = *(const bf16x8*)(
          Qb + ((size_t)bh * 832 + q0 + w * 32 + mt * 16 + (lane & 15)) * 256 +
          kf * 32 + (lane >> 4) * 8);

  float mq[2][4], li[2][4];
#pragma unroll
  for (int mt = 0; mt < 2; ++mt)
#pragma unroll
    for (int r = 0; r < 4; ++r) {
      int q = q0 + w * 32 + mt * 16 + ((lane >> 4) << 2) + r;
      mq[mt][r] = Marr[(size_t)bh * 832 + q];
      li[mt][r] = 1.0f / Larr[(size_t)bh * 832 + q];
    }

  f32x4 oa[2][16] = {};

  for (int kt = 0; kt < 26; ++kt) {
    __syncthreads();
    stage_k_tile(Ksrc + kt * 32 * 256, Ks, t);
    stage_v_tile(Vsrc + kt * 32, Vs, t);
    __syncthreads();

    f32x4 sa[2][2] = {};
    s_mfma(qf, Ks, lane, sa);

    // P = exp(s+mask-m)/l -> bf16 -> Ps (wave-private, swizzled)
#pragma unroll
    for (int mt = 0; mt < 2; ++mt)
#pragma unroll
      for (int r = 0; r < 4; ++r) {
        int prow = mt * 16 + ((lane >> 4) << 2) + r;
        int q = q0 + w * 32 + prow;
        const float* mrp = Mrow + (size_t)q * 832 + kt * 32 + (lane & 15);
#pragma unroll
        for (int nt = 0; nt < 2; ++nt) {
          int kcol = nt * 16 + (lane & 15);
          float v = sa[mt][nt][r] + mrp[nt * 16];
          float pv = __expf(v - mq[mt][r]) * li[mt][r];
          int slot = (kcol >> 3) ^ ((prow >> 2) & 3);
          Ps[wbase + prow * 32 + slot * 8 + (kcol & 7)] = f2bf(pv);
        }
      }

    // PV: O(32q x 256dh) += P(32q x 32k) @ V(32k x 256dh)
    bf16x8 pa[2];
#pragma unroll
    for (int mt = 0; mt < 2; ++mt) {
      int row = mt * 16 + (lane & 15);
      int slot = (lane >> 4) ^ ((row >> 2) & 3);
      pa[mt] = *(const bf16x8*)(Ps + wbase + row * 32 + slot * 8);
    }
#pragma unroll
    for (int nt = 0; nt < 16; ++nt) {
      bf16x8 vb = *(const bf16x8*)(
          Vs + (nt * 16 + (lane & 15)) * 32 + (lane >> 4) * 8);
#pragma unroll
      for (int mt = 0; mt < 2; ++mt)
        oa[mt][nt] = __builtin_amdgcn_mfma_f32_16x16x32_bf16(
            pa[mt], vb, oa[mt][nt], 0, 0, 0);
    }
  }

  // store O -> AO (b, l, h*256+dh) bf16
#pragma unroll
  for (int mt = 0; mt < 2; ++mt)
#pragma unroll
    for (int r = 0; r < 4; ++r) {
      size_t l = q0 + w * 32 + mt * 16 + ((lane >> 4) << 2) + r;
      u16* dst = AO + ((size_t)b * 832 + l) * 2048 + h * 256 + (lane & 15);
#pragma unroll
      for (int nt = 0; nt < 16; ++nt)
        dst[nt * 16] = f2bf(oa[mt][nt][r]);
    }
}

// ---------------------------------------------------------------------------
// Output projection: AO rows @ Wt^T -> f32 out (Kdim = 2048)
// ---------------------------------------------------------------------------
__global__ __launch_bounds__(256) void g_oproj(
    const u16* __restrict__ AO, const u16* __restrict__ Wt,
    float* __restrict__ C, int N, int rows_pb, int l_off)
{
  __shared__ u16 As[4096], Bs[4096];
  const int t = threadIdx.x;
  const int m0 = blockIdx.y * 128, n0 = blockIdx.x * 128;
  const int r0 = t >> 2;
  const int cs = ((t & 3) ^ (r0 & 3)) * 8;
  int mr0 = m0 + r0, mr1 = m0 + r0 + 64;
  int ba = mr0 / rows_pb, bb = mr1 / rows_pb;
  const u16* a0 = AO + ((size_t)ba * 832 + (mr0 - ba * rows_pb) + l_off) * 2048 + cs;
  const u16* a1 = AO + ((size_t)bb * 832 + (mr1 - bb * rows_pb) + l_off) * 2048 + cs;
  const u16* b0 = Wt + (size_t)(n0 + r0) * 2048 + cs;
  const u16* b1 = Wt + (size_t)(n0 + r0 + 64) * 2048 + cs;

  f32x4 acc[4][4] = {};
  gemm128(a0, a1, b0, b1, 64, t, As, Bs, acc);

  const int lane = t & 63;
  const int rbase = m0 + (t >> 7) * 64 + ((lane >> 4) << 2);
  const int cbase = n0 + ((t >> 6) & 1) * 64 + (lane & 15);
#pragma unroll
  for (int mt = 0; mt < 4; ++mt)
#pragma unroll
    for (int r = 0; r < 4; ++r) {
      size_t m = rbase + mt * 16 + r;
#pragma unroll
      for (int nt = 0; nt < 4; ++nt)
        C[m * N + cbase + nt * 16] = acc[mt][nt][r];
    }
}

// ---------------------------------------------------------------------------
extern "C" void kernel_launch(void* const* d_in, const int* in_sizes, int n_in,
                              void* d_out, int out_size, void* d_ws, size_t ws_size,
                              hipStream_t stream)
{
  const float* vlm_h = (const float*)d_in[0];
  const float* exp_h = (const float*)d_in[1];
  const float* mask  = (const float*)d_in[2];
  const int*   pos   = (const int*)d_in[3];
  const float* wq_v  = (const float*)d_in[4];
  const float* wk_v  = (const float*)d_in[5];
  const float* wv_v  = (const float*)d_in[6];
  const float* wo_v  = (const float*)d_in[7];
  const float* wq_e  = (const float*)d_in[8];
  const float* wk_e  = (const float*)d_in[9];
  const float* wv_e  = (const float*)d_in[10];
  const float* wo_e  = (const float*)d_in[11];
  float* out = (float*)d_out;

  // ---- workspace layout (~118 MB, no aliasing) ----
  u16* U = (u16*)d_ws;
  u16* Xv  = U; U += (size_t)4 * 768 * 2048;
  u16* Xe  = U; U += (size_t)4 * 64 * 1024;
  u16* Wqv = U; U += (size_t)2048 * 2048;
  u16* Wkv = U; U += (size_t)2048 * 2048;
  u16* Wvv = U; U += (size_t)2048 * 2048;
  u16* Wqe = U; U += (size_t)1024 * 2048;
  u16* Wke = U; U += (size_t)1024 * 2048;
  u16* Wve = U; U += (size_t)1024 * 2048;
  u16* Wov = U; U += (size_t)2048 * 2048;
  u16* Woe = U; U += (size_t)1024 * 2048;
  u16* Qb  = U; U += (size_t)32 * 832 * 256;
  u16* Kb  = U; U += (size_t)32 * 832 * 256;
  u16* Vt  = U; U += (size_t)32 * 256 * 832;
  u16* AO  = U; U += (size_t)4 * 832 * 2048;
  float* Marr = (float*)U;
  float* Larr = Marr + (size_t)32 * 832;

  const dim3 blk(256);

  g_cvt<<<dim3(1572864 / 256), blk, 0, stream>>>(vlm_h, Xv, 1572864);
  g_cvt<<<dim3(65536 / 256),   blk, 0, stream>>>(exp_h, Xe, 65536);

  g_transpose<<<dim3(64, 64), blk, 0, stream>>>(wq_v, Wqv, 2048, 2048);
  g_transpose<<<dim3(64, 64), blk, 0, stream>>>(wk_v, Wkv, 2048, 2048);
  g_transpose<<<dim3(64, 64), blk, 0, stream>>>(wv_v, Wvv, 2048, 2048);
  g_transpose<<<dim3(64, 64), blk, 0, stream>>>(wo_v, Wov, 2048, 2048);
  g_transpose<<<dim3(64, 32), blk, 0, stream>>>(wq_e, Wqe, 1024, 2048);
  g_transpose<<<dim3(64, 32), blk, 0, stream>>>(wk_e, Wke, 1024, 2048);
  g_transpose<<<dim3(64, 32), blk, 0, stream>>>(wv_e, Wve, 1024, 2048);
  g_transpose<<<dim3(32, 64), blk, 0, stream>>>(wo_e, Woe, 2048, 1024);

  g_proj_qk<<<dim3(16, 24), blk, 0, stream>>>(Xv, Wqv, Qb, 2048, 768, 0);
  g_proj_qk<<<dim3(16, 2),  blk, 0, stream>>>(Xe, Wqe, Qb, 1024, 64, 768);
  g_proj_qk<<<dim3(16, 24), blk, 0, stream>>>(Xv, Wkv, Kb, 2048, 768, 0);
  g_proj_qk<<<dim3(16, 2),  blk, 0, stream>>>(Xe, Wke, Kb, 1024, 64, 768);
  g_proj_v <<<dim3(16, 24), blk, 0, stream>>>(Xv, Wvv, Vt, 2048, 768, 0);
  g_proj_v <<<dim3(16, 2),  blk, 0, stream>>>(Xe, Wve, Vt, 1024, 64, 768);

  g_rope<<<dim3(32 * 832), dim3(128), 0, stream>>>(Qb, Kb, pos);

  // fused attention: stats pass + apply/PV pass (no S materialization)
  g_stats  <<<dim3(13, 32), dim3(128), 0, stream>>>(Qb, Kb, mask, Marr, Larr);
  g_attn_pv<<<dim3(13, 32), dim3(128), 0, stream>>>(Qb, Kb, Vt, mask,
                                                    Marr, Larr, AO);

  g_oproj<<<dim3(16, 24), blk, 0, stream>>>(AO, Wov, out, 2048, 768, 0);
  g_oproj<<<dim3(8, 2),   blk, 0, stream>>>(AO, Woe, out + (size_t)4 * 768 * 2048,
                                            1024, 64, 768);
}

// Round 6
// 577.500 us; speedup vs baseline: 3.9230x; 1.1895x over previous
//
#include <hip/hip_runtime.h>

typedef unsigned short u16;
using bf16x8 = __attribute__((ext_vector_type(8))) __bf16;
using f32x4  = __attribute__((ext_vector_type(4))) float;

// ---------------- helpers ----------------
__device__ __forceinline__ u16 f2bf(float f) {
  unsigned u = __builtin_bit_cast(unsigned, f);
  u += 0x7FFFu + ((u >> 16) & 1u);       // round-to-nearest-even
  return (u16)(u >> 16);
}
__device__ __forceinline__ float bf2f(u16 s) {
  unsigned u = ((unsigned)s) << 16;
  return __builtin_bit_cast(float, u);
}
__device__ __forceinline__ void lds16(const void* g, void* l) {
  __builtin_amdgcn_global_load_lds(
      (const __attribute__((address_space(1))) void*)g,
      (__attribute__((address_space(3))) void*)l, 16, 0, 0);
}

// ---------------------------------------------------------------------------
// 128x128 bf16 NT GEMM core (round-3 proven). BM=BN=128, BK=32, 256 thr.
// ---------------------------------------------------------------------------
__device__ __forceinline__ void gemm128(
    const u16* a0, const u16* a1, const u16* b0, const u16* b1,
    int ksteps, int t, u16* As, u16* Bs, f32x4 acc[4][4])
{
  const int lane = t & 63;
  u16* dA0 = As + t * 8;
  u16* dA1 = As + t * 8 + 2048;
  u16* dB0 = Bs + t * 8;
  u16* dB1 = Bs + t * 8 + 2048;

  const int wm = t >> 7;
  const int wn = (t >> 6) & 1;
  const int swz = (((lane >> 4) ^ (lane & 3)) * 8);
  const int fa = (wm * 64 + (lane & 15)) * 32 + swz;
  const int fb = (wn * 64 + (lane & 15)) * 32 + swz;

  for (int ks = 0; ks < ksteps; ++ks) {
    lds16(a0, dA0);
    lds16(a1, dA1);
    lds16(b0, dB0);
    lds16(b1, dB1);
    a0 += 32; a1 += 32; b0 += 32; b1 += 32;
    __syncthreads();
    bf16x8 af[4], bfr[4];
#pragma unroll
    for (int i = 0; i < 4; ++i) af[i]  = *(const bf16x8*)(As + fa + i * 512);
#pragma unroll
    for (int i = 0; i < 4; ++i) bfr[i] = *(const bf16x8*)(Bs + fb + i * 512);
#pragma unroll
    for (int mt = 0; mt < 4; ++mt)
#pragma unroll
      for (int nt = 0; nt < 4; ++nt)
        acc[mt][nt] = __builtin_amdgcn_mfma_f32_16x16x32_bf16(
            af[mt], bfr[nt], acc[mt][nt], 0, 0, 0);
    __syncthreads();
  }
}
// C/D layout: col = lane&15, row = (lane>>4)*4 + reg   [m89-verified]

// ---------------------------------------------------------------------------
// Fused prep: z<8 -> weight transpose jobs, z=8/9 -> activation f32->bf16 cvt
// ---------------------------------------------------------------------------
struct PrepArgs {
  const float* tsrc[8]; u16* tdst[8]; int tK[8]; int tN[8];
  const float* csrc[2]; u16* cdst[2]; int cn4[2];
};

__global__ __launch_bounds__(256) void g_prep(PrepArgs a)
{
  __shared__ float T[32][33];
  const int z = blockIdx.z;
  if (z < 8) {
    const int Krows = a.tK[z], Ncols = a.tN[z];
    const int k0 = blockIdx.y * 32, n0 = blockIdx.x * 32;
    if (k0 >= Krows || n0 >= Ncols) return;
    const float* W = a.tsrc[z];
    u16* Wt = a.tdst[z];
    const int tx = threadIdx.x & 31, ty = threadIdx.x >> 5;
#pragma unroll
    for (int r = 0; r < 4; ++r)
      T[ty + r * 8][tx] = W[(size_t)(k0 + ty + r * 8) * Ncols + n0 + tx];
    __syncthreads();
#pragma unroll
    for (int r = 0; r < 4; ++r)
      Wt[(size_t)(n0 + ty + r * 8) * Krows + k0 + tx] = f2bf(T[tx][ty + r * 8]);
  } else {
    const int j = z - 8;
    const int n4 = a.cn4[j];
    const float* X = a.csrc[j];
    u16* Y = a.cdst[j];
    const int blk = blockIdx.y * gridDim.x + blockIdx.x;
    const int stride = gridDim.x * gridDim.y * 256;
    for (int i = blk * 256 + threadIdx.x; i < n4; i += stride) {
      float4 f = ((const float4*)X)[i];
      ushort4 u;
      u.x = f2bf(f.x); u.y = f2bf(f.y); u.z = f2bf(f.z); u.w = f2bf(f.w);
      ((ushort4*)Y)[i] = u;
    }
  }
}

// ---------------------------------------------------------------------------
// Q/K projection -> (bh, 832, 256) bf16
// ---------------------------------------------------------------------------
__global__ __launch_bounds__(256) void g_proj_qk(
    const u16* __restrict__ X, const u16* __restrict__ Wt,
    u16* __restrict__ Out, int Kdim, int rows_pb, int l_off)
{
  __shared__ u16 As[4096], Bs[4096];
  const int t = threadIdx.x;
  const int m0 = blockIdx.y * 128, n0 = blockIdx.x * 128;
  const int r0 = t >> 2;
  const int cs = ((t & 3) ^ (r0 & 3)) * 8;
  const u16* a0 = X + (size_t)(m0 + r0) * Kdim + cs;
  const u16* a1 = X + (size_t)(m0 + r0 + 64) * Kdim + cs;
  const u16* b0 = Wt + (size_t)(n0 + r0) * Kdim + cs;
  const u16* b1 = Wt + (size_t)(n0 + r0 + 64) * Kdim + cs;

  f32x4 acc[4][4] = {};
  gemm128(a0, a1, b0, b1, Kdim >> 5, t, As, Bs, acc);

  const int lane = t & 63;
  const int rbase = m0 + (t >> 7) * 64 + ((lane >> 4) << 2);
  const int cbase = n0 + ((t >> 6) & 1) * 64 + (lane & 15);
#pragma unroll
  for (int mt = 0; mt < 4; ++mt) {
#pragma unroll
    for (int r = 0; r < 4; ++r) {
      int m = rbase + mt * 16 + r;
      int b = m / rows_pb;
      int l = m - b * rows_pb + l_off;
#pragma unroll
      for (int nt = 0; nt < 4; ++nt) {
        int n = cbase + nt * 16;
        Out[(((size_t)(b * 8 + (n >> 8))) * 832 + l) * 256 + (n & 255)] =
            f2bf(acc[mt][nt][r]);
      }
    }
  }
}

// ---------------------------------------------------------------------------
// V projection -> Vt (bh, 256, 832) bf16 (dh-major)
// ---------------------------------------------------------------------------
__global__ __launch_bounds__(256) void g_proj_v(
    const u16* __restrict__ X, const u16* __restrict__ Wt,
    u16* __restrict__ Vt, int Kdim, int rows_pb, int l_off)
{
  __shared__ u16 As[4096], Bs[4096];
  const int t = threadIdx.x;
  const int m0 = blockIdx.y * 128, n0 = blockIdx.x * 128;
  const int r0 = t >> 2;
  const int cs = ((t & 3) ^ (r0 & 3)) * 8;
  const u16* a0 = X + (size_t)(m0 + r0) * Kdim + cs;
  const u16* a1 = X + (size_t)(m0 + r0 + 64) * Kdim + cs;
  const u16* b0 = Wt + (size_t)(n0 + r0) * Kdim + cs;
  const u16* b1 = Wt + (size_t)(n0 + r0 + 64) * Kdim + cs;

  f32x4 acc[4][4] = {};
  gemm128(a0, a1, b0, b1, Kdim >> 5, t, As, Bs, acc);

  const int lane = t & 63;
  const int rbase = m0 + (t >> 7) * 64 + ((lane >> 4) << 2);
  const int cbase = n0 + ((t >> 6) & 1) * 64 + (lane & 15);
#pragma unroll
  for (int mt = 0; mt < 4; ++mt) {
    int mb = rbase + mt * 16;
    int b = mb / rows_pb;
    int l = mb - b * rows_pb + l_off;
#pragma unroll
    for (int nt = 0; nt < 4; ++nt) {
      int n = cbase + nt * 16;
      ushort4 p;
      p.x = f2bf(acc[mt][nt][0]); p.y = f2bf(acc[mt][nt][1]);
      p.z = f2bf(acc[mt][nt][2]); p.w = f2bf(acc[mt][nt][3]);
      *(ushort4*)&Vt[(((size_t)(b * 8 + (n >> 8))) * 256 + (n & 255)) * 832 + l] = p;
    }
  }
}

// ---------------------------------------------------------------------------
// RoPE in place on bf16 Q,K (bh, 832, 256). Q additionally scaled by 1/16.
// ---------------------------------------------------------------------------
__global__ __launch_bounds__(128) void g_rope(
    u16* __restrict__ Q, u16* __restrict__ Kx, const int* __restrict__ pos)
{
  const int blk = blockIdx.x;
  const int l = blk % 832, bh = blk / 832, b = bh >> 3;
  const int i = threadIdx.x;
  const float p = (float)pos[b * 832 + l];
  const float inv = exp2f(-(float)i * 0.103810252965229910f);  // log2(1e4)/128
  const float ang = p * inv;
  const float c = cosf(ang), s = sinf(ang);
  const size_t base = ((size_t)bh * 832 + l) * 256;

  float x1 = bf2f(Q[base + i]), x2 = bf2f(Q[base + i + 128]);
  Q[base + i]       = f2bf((x1 * c - x2 * s) * 0.0625f);
  Q[base + i + 128] = f2bf((x2 * c + x1 * s) * 0.0625f);
  x1 = bf2f(Kx[base + i]); x2 = bf2f(Kx[base + i + 128]);
  Kx[base + i]       = f2bf(x1 * c - x2 * s);
  Kx[base + i + 128] = f2bf(x2 * c + x1 * s);
}

// ---------------------------------------------------------------------------
// Single-pass flash attention. Grid 416 (XCD-swizzled), block 256 (4 waves).
// Each wave owns 16 q-rows; block q-tile = 64; key-tile = 32; 26 tiles.
// K LDS: [32 seq][32 chunks], slot = chunk ^ (row&7).
// V LDS: [128 rows][8 chunks] (64 u16/row): chunk lc: dh = 2*row + (lc>>2),
//        seq-chunk = lc&3, slot = lc ^ (row&7).
// P LDS: per-wave 16x32, slot = (col>>3) ^ ((row>>2)&3).
// ---------------------------------------------------------------------------
__global__ __launch_bounds__(256) void g_flash(
    const u16* __restrict__ Qb, const u16* __restrict__ Kb,
    const u16* __restrict__ Vt, const float* __restrict__ mask,
    u16* __restrict__ AO)
{
  __shared__ __align__(16) u16 Ks[8192];
  __shared__ __align__(16) u16 Vs[8192];
  __shared__ __align__(16) u16 Ps[2048];
  const int t = threadIdx.x;
  const int lane = t & 63, w = t >> 6, quad = lane >> 4;
  const int wb = w * 512;

  // XCD swizzle: all 13 q-tiles of a bh land on one XCD (id%8 heuristic)
  const int id = blockIdx.x;
  const int x = id & 7, k = id >> 3;          // k in [0,52)
  const int bh = x + 8 * (k / 13);
  const int q0 = (k % 13) * 64;
  const int b = bh >> 3, h = bh & 7;

  const u16* Ksrc = Kb + (size_t)bh * 832 * 256;
  const u16* Vsrc = Vt + (size_t)bh * 256 * 832;
  const float* Mrow = mask + (size_t)b * 832 * 832;

  // Q fragments: 16 rows x 256 dh per wave
  bf16x8 qf[8];
#pragma unroll
  for (int kf = 0; kf < 8; ++kf)
    qf[kf] = *(const bf16x8*)(
        Qb + ((size_t)bh * 832 + q0 + w * 16 + (lane & 15)) * 256 +
        kf * 32 + quad * 8);

  float mrun[4], lrun[4];
#pragma unroll
  for (int r = 0; r < 4; ++r) { mrun[r] = -3e38f; lrun[r] = 0.f; }
  f32x4 oa[16] = {};

  for (int kt = 0; kt < 26; ++kt) {
    __syncthreads();
    // stage K tile (16 KB) + V tile (16 KB), 4 chunks each per thread
#pragma unroll
    for (int p = 0; p < 4; ++p) {
      int c = p * 256 + t;
      int row = c >> 5, chk = c & 31;
      lds16(Ksrc + (size_t)(kt * 32 + row) * 256 + ((chk ^ (row & 7)) * 8),
            Ks + c * 8);
    }
#pragma unroll
    for (int p = 0; p < 4; ++p) {
      int c = p * 256 + t;
      int row = c >> 3;
      int lc = (c & 7) ^ (row & 7);
      int dh = 2 * row + (lc >> 2);
      lds16(Vsrc + (size_t)dh * 832 + kt * 32 + (lc & 3) * 8, Vs + c * 8);
    }
    __syncthreads();

    // S = Q @ K^T  (16 q x 32 k per wave)
    f32x4 sa[2] = {};
#pragma unroll
    for (int ks = 0; ks < 8; ++ks)
#pragma unroll
      for (int nt = 0; nt < 2; ++nt) {
        int krow = nt * 16 + (lane & 15);
        bf16x8 kb = *(const bf16x8*)(
            Ks + krow * 256 + (((ks * 4 + quad) ^ (krow & 7)) * 8));
        sa[nt] = __builtin_amdgcn_mfma_f32_16x16x32_bf16(qf[ks], kb, sa[nt], 0, 0, 0);
      }

    // online softmax update + unnormalized P -> Ps
    float alpha[4];
#pragma unroll
    for (int r = 0; r < 4; ++r) {
      int prow = quad * 4 + r;
      int q = q0 + w * 16 + prow;
      const float* mrp = Mrow + (size_t)q * 832 + kt * 32 + (lane & 15);
      float v0 = sa[0][r] + mrp[0];
      float v1 = sa[1][r] + mrp[16];
      float mx = fmaxf(v0, v1);
      mx = fmaxf(mx, __shfl_xor(mx, 1));
      mx = fmaxf(mx, __shfl_xor(mx, 2));
      mx = fmaxf(mx, __shfl_xor(mx, 4));
      mx = fmaxf(mx, __shfl_xor(mx, 8));
      float mn = fmaxf(mrun[r], mx);
      float al = __expf(mrun[r] - mn);
      float p0 = __expf(v0 - mn), p1 = __expf(v1 - mn);
      float rs = p0 + p1;
      rs += __shfl_xor(rs, 1);
      rs += __shfl_xor(rs, 2);
      rs += __shfl_xor(rs, 4);
      rs += __shfl_xor(rs, 8);
      lrun[r] = lrun[r] * al + rs;
      mrun[r] = mn;
      alpha[r] = al;
      int s0 = ((lane >> 3) & 1) ^ quad;          // col = lane&15      (chunk 0/1)
      int s1 = (2 | ((lane >> 3) & 1)) ^ quad;    // col = lane&15 + 16 (chunk 2/3)
      Ps[wb + prow * 32 + s0 * 8 + (lane & 7)] = f2bf(p0);
      Ps[wb + prow * 32 + s1 * 8 + (lane & 7)] = f2bf(p1);
    }

    // rescale O accumulators
#pragma unroll
    for (int nt = 0; nt < 16; ++nt)
#pragma unroll
      for (int r = 0; r < 4; ++r) oa[nt][r] *= alpha[r];

    // PV: O(16q x 256dh) += P(16q x 32k) @ V(32k x 256dh)
    int prow2 = lane & 15;
    bf16x8 pa = *(const bf16x8*)(
        Ps + wb + prow2 * 32 + ((quad ^ ((prow2 >> 2) & 3)) * 8));
#pragma unroll
    for (int nt = 0; nt < 16; ++nt) {
      int dh = nt * 16 + (lane & 15);
      int row = dh >> 1;
      int lc = ((dh & 1) << 2) | quad;
      // Vs row stride is 64 u16 (8 chunks x 8 u16)  [round-5 bug: was *128]
      bf16x8 vb = *(const bf16x8*)(Vs + row * 64 + ((lc ^ (row & 7)) * 8));
      oa[nt] = __builtin_amdgcn_mfma_f32_16x16x32_bf16(pa, vb, oa[nt], 0, 0, 0);
    }
  }

  // normalize and store: AO(b, l, h*256+dh) bf16
  float linv[4];
#pragma unroll
  for (int r = 0; r < 4; ++r) linv[r] = 1.0f / lrun[r];
#pragma unroll
  for (int r = 0; r < 4; ++r) {
    size_t l = q0 + w * 16 + quad * 4 + r;
    u16* dst = AO + ((size_t)b * 832 + l) * 2048 + h * 256 + (lane & 15);
#pragma unroll
    for (int nt = 0; nt < 16; ++nt)
      dst[nt * 16] = f2bf(oa[nt][r] * linv[r]);
  }
}

// ---------------------------------------------------------------------------
// Output projection: AO rows @ Wt^T -> f32 out (Kdim = 2048)
// ---------------------------------------------------------------------------
__global__ __launch_bounds__(256) void g_oproj(
    const u16* __restrict__ AO, const u16* __restrict__ Wt,
    float* __restrict__ C, int N, int rows_pb, int l_off)
{
  __shared__ u16 As[4096], Bs[4096];
  const int t = threadIdx.x;
  const int m0 = blockIdx.y * 128, n0 = blockIdx.x * 128;
  const int r0 = t >> 2;
  const int cs = ((t & 3) ^ (r0 & 3)) * 8;
  int mr0 = m0 + r0, mr1 = m0 + r0 + 64;
  int ba = mr0 / rows_pb, bb = mr1 / rows_pb;
  const u16* a0 = AO + ((size_t)ba * 832 + (mr0 - ba * rows_pb) + l_off) * 2048 + cs;
  const u16* a1 = AO + ((size_t)bb * 832 + (mr1 - bb * rows_pb) + l_off) * 2048 + cs;
  const u16* b0 = Wt + (size_t)(n0 + r0) * 2048 + cs;
  const u16* b1 = Wt + (size_t)(n0 + r0 + 64) * 2048 + cs;

  f32x4 acc[4][4] = {};
  gemm128(a0, a1, b0, b1, 64, t, As, Bs, acc);

  const int lane = t & 63;
  const int rbase = m0 + (t >> 7) * 64 + ((lane >> 4) << 2);
  const int cbase = n0 + ((t >> 6) & 1) * 64 + (lane & 15);
#pragma unroll
  for (int mt = 0; mt < 4; ++mt)
#pragma unroll
    for (int r = 0; r < 4; ++r) {
      size_t m = rbase + mt * 16 + r;
#pragma unroll
      for (int nt = 0; nt < 4; ++nt)
        C[m * N + cbase + nt * 16] = acc[mt][nt][r];
    }
}

// ---------------------------------------------------------------------------
extern "C" void kernel_launch(void* const* d_in, const int* in_sizes, int n_in,
                              void* d_out, int out_size, void* d_ws, size_t ws_size,
                              hipStream_t stream)
{
  const float* vlm_h = (const float*)d_in[0];
  const float* exp_h = (const float*)d_in[1];
  const float* mask  = (const float*)d_in[2];
  const int*   pos   = (const int*)d_in[3];
  const float* wq_v  = (const float*)d_in[4];
  const float* wk_v  = (const float*)d_in[5];
  const float* wv_v  = (const float*)d_in[6];
  const float* wo_v  = (const float*)d_in[7];
  const float* wq_e  = (const float*)d_in[8];
  const float* wk_e  = (const float*)d_in[9];
  const float* wv_e  = (const float*)d_in[10];
  const float* wo_e  = (const float*)d_in[11];
  float* out = (float*)d_out;

  // ---- workspace layout (~118 MB) ----
  u16* U = (u16*)d_ws;
  u16* Xv  = U; U += (size_t)4 * 768 * 2048;
  u16* Xe  = U; U += (size_t)4 * 64 * 1024;
  u16* Wqv = U; U += (size_t)2048 * 2048;
  u16* Wkv = U; U += (size_t)2048 * 2048;
  u16* Wvv = U; U += (size_t)2048 * 2048;
  u16* Wqe = U; U += (size_t)1024 * 2048;
  u16* Wke = U; U += (size_t)1024 * 2048;
  u16* Wve = U; U += (size_t)1024 * 2048;
  u16* Wov = U; U += (size_t)2048 * 2048;
  u16* Woe = U; U += (size_t)1024 * 2048;
  u16* Qb  = U; U += (size_t)32 * 832 * 256;
  u16* Kb  = U; U += (size_t)32 * 832 * 256;
  u16* Vt  = U; U += (size_t)32 * 256 * 832;
  u16* AO  = U; U += (size_t)4 * 832 * 2048;

  const dim3 blk(256);

  // fused prep: 8 transposes + 2 converts in one launch
  PrepArgs pa;
  pa.tsrc[0] = wq_v; pa.tdst[0] = Wqv; pa.tK[0] = 2048; pa.tN[0] = 2048;
  pa.tsrc[1] = wk_v; pa.tdst[1] = Wkv; pa.tK[1] = 2048; pa.tN[1] = 2048;
  pa.tsrc[2] = wv_v; pa.tdst[2] = Wvv; pa.tK[2] = 2048; pa.tN[2] = 2048;
  pa.tsrc[3] = wo_v; pa.tdst[3] = Wov; pa.tK[3] = 2048; pa.tN[3] = 2048;
  pa.tsrc[4] = wq_e; pa.tdst[4] = Wqe; pa.tK[4] = 1024; pa.tN[4] = 2048;
  pa.tsrc[5] = wk_e; pa.tdst[5] = Wke; pa.tK[5] = 1024; pa.tN[5] = 2048;
  pa.tsrc[6] = wv_e; pa.tdst[6] = Wve; pa.tK[6] = 1024; pa.tN[6] = 2048;
  pa.tsrc[7] = wo_e; pa.tdst[7] = Woe; pa.tK[7] = 2048; pa.tN[7] = 1024;
  pa.csrc[0] = vlm_h; pa.cdst[0] = Xv; pa.cn4[0] = 1572864;
  pa.csrc[1] = exp_h; pa.cdst[1] = Xe; pa.cn4[1] = 65536;
  g_prep<<<dim3(64, 64, 10), blk, 0, stream>>>(pa);

  // projections
  g_proj_qk<<<dim3(16, 24), blk, 0, stream>>>(Xv, Wqv, Qb, 2048, 768, 0);
  g_proj_qk<<<dim3(16, 2),  blk, 0, stream>>>(Xe, Wqe, Qb, 1024, 64, 768);
  g_proj_qk<<<dim3(16, 24), blk, 0, stream>>>(Xv, Wkv, Kb, 2048, 768, 0);
  g_proj_qk<<<dim3(16, 2),  blk, 0, stream>>>(Xe, Wke, Kb, 1024, 64, 768);
  g_proj_v <<<dim3(16, 24), blk, 0, stream>>>(Xv, Wvv, Vt, 2048, 768, 0);
  g_proj_v <<<dim3(16, 2),  blk, 0, stream>>>(Xe, Wve, Vt, 1024, 64, 768);

  g_rope<<<dim3(32 * 832), dim3(128), 0, stream>>>(Qb, Kb, pos);

  // single-pass flash attention
  g_flash<<<dim3(416), blk, 0, stream>>>(Qb, Kb, Vt, mask, AO);

  // output projections
  g_oproj<<<dim3(16, 24), blk, 0, stream>>>(AO, Wov, out, 2048, 768, 0);
  g_oproj<<<dim3(8, 2),   blk, 0, stream>>>(AO, Woe, out + (size_t)4 * 768 * 2048,
                                            1024, 64, 768);
}

// Round 7
// 458.140 us; speedup vs baseline: 4.9451x; 1.2605x over previous
//
#include <hip/hip_runtime.h>

typedef unsigned short u16;
using bf16x8 = __attribute__((ext_vector_type(8))) __bf16;
using f32x4  = __attribute__((ext_vector_type(4))) float;

// ---------------- helpers ----------------
__device__ __forceinline__ u16 f2bf(float f) {
  unsigned u = __builtin_bit_cast(unsigned, f);
  u += 0x7FFFu + ((u >> 16) & 1u);       // round-to-nearest-even
  return (u16)(u >> 16);
}
__device__ __forceinline__ float bf2f(u16 s) {
  unsigned u = ((unsigned)s) << 16;
  return __builtin_bit_cast(float, u);
}
__device__ __forceinline__ void lds16(const void* g, void* l) {
  __builtin_amdgcn_global_load_lds(
      (const __attribute__((address_space(1))) void*)g,
      (__attribute__((address_space(3))) void*)l, 16, 0, 0);
}

// ---------------------------------------------------------------------------
// 128x128 bf16 NT GEMM core (round-3 proven). BM=BN=128, BK=32, 256 thr.
// ---------------------------------------------------------------------------
__device__ __forceinline__ void gemm128(
    const u16* a0, const u16* a1, const u16* b0, const u16* b1,
    int ksteps, int t, u16* As, u16* Bs, f32x4 acc[4][4])
{
  const int lane = t & 63;
  u16* dA0 = As + t * 8;
  u16* dA1 = As + t * 8 + 2048;
  u16* dB0 = Bs + t * 8;
  u16* dB1 = Bs + t * 8 + 2048;

  const int wm = t >> 7;
  const int wn = (t >> 6) & 1;
  const int swz = (((lane >> 4) ^ (lane & 3)) * 8);
  const int fa = (wm * 64 + (lane & 15)) * 32 + swz;
  const int fb = (wn * 64 + (lane & 15)) * 32 + swz;

  for (int ks = 0; ks < ksteps; ++ks) {
    lds16(a0, dA0);
    lds16(a1, dA1);
    lds16(b0, dB0);
    lds16(b1, dB1);
    a0 += 32; a1 += 32; b0 += 32; b1 += 32;
    __syncthreads();
    bf16x8 af[4], bfr[4];
#pragma unroll
    for (int i = 0; i < 4; ++i) af[i]  = *(const bf16x8*)(As + fa + i * 512);
#pragma unroll
    for (int i = 0; i < 4; ++i) bfr[i] = *(const bf16x8*)(Bs + fb + i * 512);
#pragma unroll
    for (int mt = 0; mt < 4; ++mt)
#pragma unroll
      for (int nt = 0; nt < 4; ++nt)
        acc[mt][nt] = __builtin_amdgcn_mfma_f32_16x16x32_bf16(
            af[mt], bfr[nt], acc[mt][nt], 0, 0, 0);
    __syncthreads();
  }
}
// C/D layout: col = lane&15, row = (lane>>4)*4 + reg   [m89-verified]

// ---------------------------------------------------------------------------
// Fused prep: z<8 -> weight transpose jobs, z=8/9 -> activation f32->bf16 cvt
// ---------------------------------------------------------------------------
struct PrepArgs {
  const float* tsrc[8]; u16* tdst[8]; int tK[8]; int tN[8];
  const float* csrc[2]; u16* cdst[2]; int cn4[2];
};

__global__ __launch_bounds__(256) void g_prep(PrepArgs a)
{
  __shared__ float T[32][33];
  const int z = blockIdx.z;
  if (z < 8) {
    const int Krows = a.tK[z], Ncols = a.tN[z];
    const int k0 = blockIdx.y * 32, n0 = blockIdx.x * 32;
    if (k0 >= Krows || n0 >= Ncols) return;
    const float* W = a.tsrc[z];
    u16* Wt = a.tdst[z];
    const int tx = threadIdx.x & 31, ty = threadIdx.x >> 5;
#pragma unroll
    for (int r = 0; r < 4; ++r)
      T[ty + r * 8][tx] = W[(size_t)(k0 + ty + r * 8) * Ncols + n0 + tx];
    __syncthreads();
#pragma unroll
    for (int r = 0; r < 4; ++r)
      Wt[(size_t)(n0 + ty + r * 8) * Krows + k0 + tx] = f2bf(T[tx][ty + r * 8]);
  } else {
    const int j = z - 8;
    const int n4 = a.cn4[j];
    const float* X = a.csrc[j];
    u16* Y = a.cdst[j];
    const int blk = blockIdx.y * gridDim.x + blockIdx.x;
    const int stride = gridDim.x * gridDim.y * 256;
    for (int i = blk * 256 + threadIdx.x; i < n4; i += stride) {
      float4 f = ((const float4*)X)[i];
      ushort4 u;
      u.x = f2bf(f.x); u.y = f2bf(f.y); u.z = f2bf(f.z); u.w = f2bf(f.w);
      ((ushort4*)Y)[i] = u;
    }
  }
}

// ---------------------------------------------------------------------------
// Fused QKV projection. Wcat = [Wq^T | Wk^T | Wv^T] (6144 x Kdim) bf16.
// z=0: vlm tokens (Kdim 2048, M 3072); z=1: exp tokens (Kdim 1024, M 256).
// Block n-range (128) lies entirely in one of Q/K/V (2048 each).
// Epilogue routes: sect 0 -> Qb, 1 -> Kb (bh,832,256); 2 -> Vt (bh,256,832).
// ---------------------------------------------------------------------------
__global__ __launch_bounds__(256) void g_proj_qkv(
    const u16* __restrict__ Xv, const u16* __restrict__ Xe,
    const u16* __restrict__ Wv_cat, const u16* __restrict__ We_cat,
    u16* __restrict__ Qb, u16* __restrict__ Kb, u16* __restrict__ Vt)
{
  __shared__ u16 As[4096], Bs[4096];
  const int z = blockIdx.z;
  const u16* X; const u16* Wt; int Kdim, rows_pb, l_off;
  if (z == 0) { X = Xv; Wt = Wv_cat; Kdim = 2048; rows_pb = 768; l_off = 0; }
  else {
    if (blockIdx.y >= 2) return;
    X = Xe; Wt = We_cat; Kdim = 1024; rows_pb = 64; l_off = 768;
  }
  const int t = threadIdx.x;
  const int m0 = blockIdx.y * 128, n0 = blockIdx.x * 128;
  const int r0 = t >> 2;
  const int cs = ((t & 3) ^ (r0 & 3)) * 8;
  const u16* a0 = X + (size_t)(m0 + r0) * Kdim + cs;
  const u16* a1 = X + (size_t)(m0 + r0 + 64) * Kdim + cs;
  const u16* b0 = Wt + (size_t)(n0 + r0) * Kdim + cs;
  const u16* b1 = Wt + (size_t)(n0 + r0 + 64) * Kdim + cs;

  f32x4 acc[4][4] = {};
  gemm128(a0, a1, b0, b1, Kdim >> 5, t, As, Bs, acc);

  const int lane = t & 63;
  const int rbase = m0 + (t >> 7) * 64 + ((lane >> 4) << 2);
  const int cbase = n0 + ((t >> 6) & 1) * 64 + (lane & 15);
  const int sect = n0 >> 11;               // block-uniform: 0=Q 1=K 2=V

  if (sect < 2) {
    u16* Out = (sect == 0) ? Qb : Kb;
#pragma unroll
    for (int mt = 0; mt < 4; ++mt) {
#pragma unroll
      for (int r = 0; r < 4; ++r) {
        int m = rbase + mt * 16 + r;
        int b = m / rows_pb;
        int l = m - b * rows_pb + l_off;
#pragma unroll
        for (int nt = 0; nt < 4; ++nt) {
          int nloc = (cbase + nt * 16) & 2047;
          Out[(((size_t)(b * 8 + (nloc >> 8))) * 832 + l) * 256 + (nloc & 255)] =
              f2bf(acc[mt][nt][r]);
        }
      }
    }
  } else {
#pragma unroll
    for (int mt = 0; mt < 4; ++mt) {
      int mb = rbase + mt * 16;
      int b = mb / rows_pb;
      int l = mb - b * rows_pb + l_off;     // 4-aligned, no batch crossing
#pragma unroll
      for (int nt = 0; nt < 4; ++nt) {
        int nloc = (cbase + nt * 16) & 2047;
        ushort4 p;
        p.x = f2bf(acc[mt][nt][0]); p.y = f2bf(acc[mt][nt][1]);
        p.z = f2bf(acc[mt][nt][2]); p.w = f2bf(acc[mt][nt][3]);
        *(ushort4*)&Vt[(((size_t)(b * 8 + (nloc >> 8))) * 256 + (nloc & 255)) * 832 + l] = p;
      }
    }
  }
}

// ---------------------------------------------------------------------------
// RoPE in place on bf16 Q,K (bh, 832, 256). Q additionally scaled by 1/16.
// ---------------------------------------------------------------------------
__global__ __launch_bounds__(128) void g_rope(
    u16* __restrict__ Q, u16* __restrict__ Kx, const int* __restrict__ pos)
{
  const int blk = blockIdx.x;
  const int l = blk % 832, bh = blk / 832, b = bh >> 3;
  const int i = threadIdx.x;
  const float p = (float)pos[b * 832 + l];
  const float inv = exp2f(-(float)i * 0.103810252965229910f);  // log2(1e4)/128
  const float ang = p * inv;
  const float c = cosf(ang), s = sinf(ang);
  const size_t base = ((size_t)bh * 832 + l) * 256;

  float x1 = bf2f(Q[base + i]), x2 = bf2f(Q[base + i + 128]);
  Q[base + i]       = f2bf((x1 * c - x2 * s) * 0.0625f);
  Q[base + i + 128] = f2bf((x2 * c + x1 * s) * 0.0625f);
  x1 = bf2f(Kx[base + i]); x2 = bf2f(Kx[base + i + 128]);
  Kx[base + i]       = f2bf(x1 * c - x2 * s);
  Kx[base + i + 128] = f2bf(x2 * c + x1 * s);
}

// ---------------------------------------------------------------------------
// Single-pass flash attention (round-6 proven). Grid 416, block 256 (4 waves).
// ---------------------------------------------------------------------------
__global__ __launch_bounds__(256) void g_flash(
    const u16* __restrict__ Qb, const u16* __restrict__ Kb,
    const u16* __restrict__ Vt, const float* __restrict__ mask,
    u16* __restrict__ AO)
{
  __shared__ __align__(16) u16 Ks[8192];
  __shared__ __align__(16) u16 Vs[8192];
  __shared__ __align__(16) u16 Ps[2048];
  const int t = threadIdx.x;
  const int lane = t & 63, w = t >> 6, quad = lane >> 4;
  const int wb = w * 512;

  // XCD swizzle: all 13 q-tiles of a bh land on one XCD (id%8 heuristic)
  const int id = blockIdx.x;
  const int x = id & 7, k = id >> 3;          // k in [0,52)
  const int bh = x + 8 * (k / 13);
  const int q0 = (k % 13) * 64;
  const int b = bh >> 3, h = bh & 7;

  const u16* Ksrc = Kb + (size_t)bh * 832 * 256;
  const u16* Vsrc = Vt + (size_t)bh * 256 * 832;
  const float* Mrow = mask + (size_t)b * 832 * 832;

  bf16x8 qf[8];
#pragma unroll
  for (int kf = 0; kf < 8; ++kf)
    qf[kf] = *(const bf16x8*)(
        Qb + ((size_t)bh * 832 + q0 + w * 16 + (lane & 15)) * 256 +
        kf * 32 + quad * 8);

  float mrun[4], lrun[4];
#pragma unroll
  for (int r = 0; r < 4; ++r) { mrun[r] = -3e38f; lrun[r] = 0.f; }
  f32x4 oa[16] = {};

  for (int kt = 0; kt < 26; ++kt) {
    __syncthreads();
#pragma unroll
    for (int p = 0; p < 4; ++p) {
      int c = p * 256 + t;
      int row = c >> 5, chk = c & 31;
      lds16(Ksrc + (size_t)(kt * 32 + row) * 256 + ((chk ^ (row & 7)) * 8),
            Ks + c * 8);
    }
#pragma unroll
    for (int p = 0; p < 4; ++p) {
      int c = p * 256 + t;
      int row = c >> 3;
      int lc = (c & 7) ^ (row & 7);
      int dh = 2 * row + (lc >> 2);
      lds16(Vsrc + (size_t)dh * 832 + kt * 32 + (lc & 3) * 8, Vs + c * 8);
    }
    __syncthreads();

    f32x4 sa[2] = {};
#pragma unroll
    for (int ks = 0; ks < 8; ++ks)
#pragma unroll
      for (int nt = 0; nt < 2; ++nt) {
        int krow = nt * 16 + (lane & 15);
        bf16x8 kb = *(const bf16x8*)(
            Ks + krow * 256 + (((ks * 4 + quad) ^ (krow & 7)) * 8));
        sa[nt] = __builtin_amdgcn_mfma_f32_16x16x32_bf16(qf[ks], kb, sa[nt], 0, 0, 0);
      }

    float alpha[4];
#pragma unroll
    for (int r = 0; r < 4; ++r) {
      int prow = quad * 4 + r;
      int q = q0 + w * 16 + prow;
      const float* mrp = Mrow + (size_t)q * 832 + kt * 32 + (lane & 15);
      float v0 = sa[0][r] + mrp[0];
      float v1 = sa[1][r] + mrp[16];
      float mx = fmaxf(v0, v1);
      mx = fmaxf(mx, __shfl_xor(mx, 1));
      mx = fmaxf(mx, __shfl_xor(mx, 2));
      mx = fmaxf(mx, __shfl_xor(mx, 4));
      mx = fmaxf(mx, __shfl_xor(mx, 8));
      float mn = fmaxf(mrun[r], mx);
      float al = __expf(mrun[r] - mn);
      float p0 = __expf(v0 - mn), p1 = __expf(v1 - mn);
      float rs = p0 + p1;
      rs += __shfl_xor(rs, 1);
      rs += __shfl_xor(rs, 2);
      rs += __shfl_xor(rs, 4);
      rs += __shfl_xor(rs, 8);
      lrun[r] = lrun[r] * al + rs;
      mrun[r] = mn;
      alpha[r] = al;
      int s0 = ((lane >> 3) & 1) ^ quad;
      int s1 = (2 | ((lane >> 3) & 1)) ^ quad;
      Ps[wb + prow * 32 + s0 * 8 + (lane & 7)] = f2bf(p0);
      Ps[wb + prow * 32 + s1 * 8 + (lane & 7)] = f2bf(p1);
    }

#pragma unroll
    for (int nt = 0; nt < 16; ++nt)
#pragma unroll
      for (int r = 0; r < 4; ++r) oa[nt][r] *= alpha[r];

    int prow2 = lane & 15;
    bf16x8 pa = *(const bf16x8*)(
        Ps + wb + prow2 * 32 + ((quad ^ ((prow2 >> 2) & 3)) * 8));
#pragma unroll
    for (int nt = 0; nt < 16; ++nt) {
      int dh = nt * 16 + (lane & 15);
      int row = dh >> 1;
      int lc = ((dh & 1) << 2) | quad;
      bf16x8 vb = *(const bf16x8*)(Vs + row * 64 + ((lc ^ (row & 7)) * 8));
      oa[nt] = __builtin_amdgcn_mfma_f32_16x16x32_bf16(pa, vb, oa[nt], 0, 0, 0);
    }
  }

  float linv[4];
#pragma unroll
  for (int r = 0; r < 4; ++r) linv[r] = 1.0f / lrun[r];
#pragma unroll
  for (int r = 0; r < 4; ++r) {
    size_t l = q0 + w * 16 + quad * 4 + r;
    u16* dst = AO + ((size_t)b * 832 + l) * 2048 + h * 256 + (lane & 15);
#pragma unroll
    for (int nt = 0; nt < 16; ++nt)
      dst[nt * 16] = f2bf(oa[nt][r] * linv[r]);
  }
}

// ---------------------------------------------------------------------------
// Fused output projection: z=0 vlm (Wov, N=2048), z=1 exp (Woe, N=1024).
// ---------------------------------------------------------------------------
__global__ __launch_bounds__(256) void g_oproj2(
    const u16* __restrict__ AO, const u16* __restrict__ Wov,
    const u16* __restrict__ Woe, float* __restrict__ out)
{
  __shared__ u16 As[4096], Bs[4096];
  const int z = blockIdx.z;
  const u16* Wt; float* C; int N, rows_pb, l_off;
  if (z == 0) { Wt = Wov; C = out; N = 2048; rows_pb = 768; l_off = 0; }
  else {
    if (blockIdx.y >= 2 || blockIdx.x >= 8) return;
    Wt = Woe; C = out + (size_t)4 * 768 * 2048; N = 1024; rows_pb = 64; l_off = 768;
  }
  const int t = threadIdx.x;
  const int m0 = blockIdx.y * 128, n0 = blockIdx.x * 128;
  const int r0 = t >> 2;
  const int cs = ((t & 3) ^ (r0 & 3)) * 8;
  int mr0 = m0 + r0, mr1 = m0 + r0 + 64;
  int ba = mr0 / rows_pb, bb = mr1 / rows_pb;
  const u16* a0 = AO + ((size_t)ba * 832 + (mr0 - ba * rows_pb) + l_off) * 2048 + cs;
  const u16* a1 = AO + ((size_t)bb * 832 + (mr1 - bb * rows_pb) + l_off) * 2048 + cs;
  const u16* b0 = Wt + (size_t)(n0 + r0) * 2048 + cs;
  const u16* b1 = Wt + (size_t)(n0 + r0 + 64) * 2048 + cs;

  f32x4 acc[4][4] = {};
  gemm128(a0, a1, b0, b1, 64, t, As, Bs, acc);

  const int lane = t & 63;
  const int rbase = m0 + (t >> 7) * 64 + ((lane >> 4) << 2);
  const int cbase = n0 + ((t >> 6) & 1) * 64 + (lane & 15);
#pragma unroll
  for (int mt = 0; mt < 4; ++mt)
#pragma unroll
    for (int r = 0; r < 4; ++r) {
      size_t m = rbase + mt * 16 + r;
#pragma unroll
      for (int nt = 0; nt < 4; ++nt)
        C[m * N + cbase + nt * 16] = acc[mt][nt][r];
    }
}

// ---------------------------------------------------------------------------
extern "C" void kernel_launch(void* const* d_in, const int* in_sizes, int n_in,
                              void* d_out, int out_size, void* d_ws, size_t ws_size,
                              hipStream_t stream)
{
  const float* vlm_h = (const float*)d_in[0];
  const float* exp_h = (const float*)d_in[1];
  const float* mask  = (const float*)d_in[2];
  const int*   pos   = (const int*)d_in[3];
  const float* wq_v  = (const float*)d_in[4];
  const float* wk_v  = (const float*)d_in[5];
  const float* wv_v  = (const float*)d_in[6];
  const float* wo_v  = (const float*)d_in[7];
  const float* wq_e  = (const float*)d_in[8];
  const float* wk_e  = (const float*)d_in[9];
  const float* wv_e  = (const float*)d_in[10];
  const float* wo_e  = (const float*)d_in[11];
  float* out = (float*)d_out;

  // ---- workspace layout (~118 MB) ----
  u16* U = (u16*)d_ws;
  u16* Xv   = U; U += (size_t)4 * 768 * 2048;
  u16* Xe   = U; U += (size_t)4 * 64 * 1024;
  u16* Wcv  = U; U += (size_t)6144 * 2048;   // [Wq_v^T | Wk_v^T | Wv_v^T]
  u16* Wce  = U; U += (size_t)6144 * 1024;   // [Wq_e^T | Wk_e^T | Wv_e^T]
  u16* Wov  = U; U += (size_t)2048 * 2048;
  u16* Woe  = U; U += (size_t)1024 * 2048;
  u16* Qb   = U; U += (size_t)32 * 832 * 256;
  u16* Kb   = U; U += (size_t)32 * 832 * 256;
  u16* Vt   = U; U += (size_t)32 * 256 * 832;
  u16* AO   = U; U += (size_t)4 * 832 * 2048;

  const dim3 blk(256);

  // fused prep: 8 transposes + 2 converts (weight transposes write into Wcat)
  PrepArgs pa;
  pa.tsrc[0] = wq_v; pa.tdst[0] = Wcv;                        pa.tK[0] = 2048; pa.tN[0] = 2048;
  pa.tsrc[1] = wk_v; pa.tdst[1] = Wcv + (size_t)2048 * 2048;  pa.tK[1] = 2048; pa.tN[1] = 2048;
  pa.tsrc[2] = wv_v; pa.tdst[2] = Wcv + (size_t)4096 * 2048;  pa.tK[2] = 2048; pa.tN[2] = 2048;
  pa.tsrc[3] = wo_v; pa.tdst[3] = Wov;                        pa.tK[3] = 2048; pa.tN[3] = 2048;
  pa.tsrc[4] = wq_e; pa.tdst[4] = Wce;                        pa.tK[4] = 1024; pa.tN[4] = 2048;
  pa.tsrc[5] = wk_e; pa.tdst[5] = Wce + (size_t)2048 * 1024;  pa.tK[5] = 1024; pa.tN[5] = 2048;
  pa.tsrc[6] = wv_e; pa.tdst[6] = Wce + (size_t)4096 * 1024;  pa.tK[6] = 1024; pa.tN[6] = 2048;
  pa.tsrc[7] = wo_e; pa.tdst[7] = Woe;                        pa.tK[7] = 2048; pa.tN[7] = 1024;
  pa.csrc[0] = vlm_h; pa.cdst[0] = Xv; pa.cn4[0] = 1572864;
  pa.csrc[1] = exp_h; pa.cdst[1] = Xe; pa.cn4[1] = 65536;
  g_prep<<<dim3(64, 64, 10), blk, 0, stream>>>(pa);

  // fused QKV projection (vlm + exp via z)
  g_proj_qkv<<<dim3(48, 24, 2), blk, 0, stream>>>(Xv, Xe, Wcv, Wce, Qb, Kb, Vt);

  g_rope<<<dim3(32 * 832), dim3(128), 0, stream>>>(Qb, Kb, pos);

  // single-pass flash attention
  g_flash<<<dim3(416), blk, 0, stream>>>(Qb, Kb, Vt, mask, AO);

  // fused output projections (vlm + exp via z)
  g_oproj2<<<dim3(16, 24, 2), blk, 0, stream>>>(AO, Wov, Woe, out);
}